// Round 1
// baseline (136.300 us; speedup 1.0000x reference)
//
#include <hip/hip_runtime.h>
#include <hip/hip_bf16.h>

typedef __attribute__((ext_vector_type(8))) short bf16x8;
typedef __attribute__((ext_vector_type(4))) float f32x4;

#define Bq 4
#define Tq 2048
#define Cq 1024
#define Dq 128
#define KT (Cq/32)   // 32 k-tiles of 32
#define NT (Dq/16)   // 8 n-tiles of 16

__device__ __forceinline__ short f2bf(float f) {
  unsigned u = __float_as_uint(f);
  u += 0x7fffu + ((u >> 16) & 1u);   // RNE; inputs are finite
  return (short)(u >> 16);
}

// x [8192][1024] fp32 -> bf16 packed in MFMA A-frag order:
// xp[((mt*KT + kt)*64 + l)*8 + j] = x[mt*16 + l%16][kt*32 + (l/16)*8 + j]
__global__ __launch_bounds__(256) void pack_x_kernel(const float* __restrict__ x,
                                                     short* __restrict__ xp) {
  int tid = blockIdx.x * 256 + threadIdx.x;      // 8192*128 threads
  int row = tid >> 7;
  int k0  = (tid & 127) << 3;
  const float4* src = reinterpret_cast<const float4*>(x + (size_t)row * Cq + k0);
  float4 v0 = src[0];
  float4 v1 = src[1];
  int mt = row >> 4, r = row & 15;
  int kt = k0 >> 5,  h = (k0 >> 3) & 3;
  int l  = h * 16 + r;
  bf16x8 o;
  o[0]=f2bf(v0.x); o[1]=f2bf(v0.y); o[2]=f2bf(v0.z); o[3]=f2bf(v0.w);
  o[4]=f2bf(v1.x); o[5]=f2bf(v1.y); o[6]=f2bf(v1.z); o[7]=f2bf(v1.w);
  reinterpret_cast<bf16x8*>(xp)[((size_t)mt * KT + kt) * 64 + l] = o;
}

// W [1024][128] fp32 -> bf16 packed in MFMA B-frag order (3 matrices):
// wp[y*16384*8 ... ] frag idx = (kt*8 + nt)*64 + l ; value = W[kt*32+(l/16)*8+j][nt*16+l%16]
// D^-0.5 folded into Wq (y==0).
__global__ __launch_bounds__(256) void pack_w_kernel(const float* __restrict__ Wq_,
                                                     const float* __restrict__ Wk_,
                                                     const float* __restrict__ Wv_,
                                                     short* __restrict__ wp) {
  int tid = blockIdx.x * 256 + threadIdx.x;      // 3*16384 threads
  int y   = tid >> 14;
  int idx = tid & 16383;
  int l   = idx & 63;
  const float* W = (y == 0) ? Wq_ : (y == 1 ? Wk_ : Wv_);
  float scale = (y == 0) ? 0.08838834764831845f : 1.0f;   // 1/sqrt(128)
  int kbase = (idx >> 9) * 32 + (l >> 4) * 8;
  int n     = ((idx >> 6) & 7) * 16 + (l & 15);
  bf16x8 o;
  #pragma unroll
  for (int j = 0; j < 8; ++j) o[j] = f2bf(W[(size_t)(kbase + j) * Dq + n] * scale);
  reinterpret_cast<bf16x8*>(wp)[tid] = o;        // == y*16384 + idx
}

// QKV GEMM: grid (64, 3). Block 256 = 4 waves, each wave 64x64 (4x4 frags of 16x16).
// No LDS: A/B frags stream coalesced from packed global buffers.
// Epilogue: y=0 -> q row-major bf16 (pre-scaled), y=1 -> k row-major, y=2 -> vT[b][d][t].
__global__ __launch_bounds__(256) void qkv_gemm_kernel(const short* __restrict__ xp,
                                                       const short* __restrict__ wp,
                                                       short* __restrict__ qb,
                                                       short* __restrict__ kb2,
                                                       short* __restrict__ vt) {
  int y  = blockIdx.y;
  int bm = blockIdx.x;
  int w  = threadIdx.x >> 6, l = threadIdx.x & 63;
  int wr = w >> 1, wc = w & 1;
  const bf16x8* A8 = reinterpret_cast<const bf16x8*>(xp);
  const bf16x8* B8 = reinterpret_cast<const bf16x8*>(wp) + (size_t)y * 16384;
  f32x4 acc[4][4] = {};
  int mt0 = bm * 8 + wr * 4;
  int nt0 = wc * 4;
  #pragma unroll 2
  for (int kt = 0; kt < KT; ++kt) {
    bf16x8 a[4], b[4];
    #pragma unroll
    for (int mi = 0; mi < 4; ++mi) a[mi] = A8[((size_t)(mt0 + mi) * KT + kt) * 64 + l];
    #pragma unroll
    for (int ni = 0; ni < 4; ++ni) b[ni] = B8[((size_t)kt * 8 + nt0 + ni) * 64 + l];
    #pragma unroll
    for (int mi = 0; mi < 4; ++mi)
      #pragma unroll
      for (int ni = 0; ni < 4; ++ni)
        acc[mi][ni] = __builtin_amdgcn_mfma_f32_16x16x32_bf16(a[mi], b[ni], acc[mi][ni], 0, 0, 0);
  }
  int g = l >> 4, c0 = l & 15;
  #pragma unroll
  for (int mi = 0; mi < 4; ++mi) {
    #pragma unroll
    for (int ni = 0; ni < 4; ++ni) {
      #pragma unroll
      for (int reg = 0; reg < 4; ++reg) {
        int m = bm * 128 + wr * 64 + mi * 16 + g * 4 + reg;
        int n = wc * 64 + ni * 16 + c0;
        short s = f2bf(acc[mi][ni][reg]);
        if (y == 0)      qb[(size_t)m * Dq + n] = s;
        else if (y == 1) kb2[(size_t)m * Dq + n] = s;
        else {
          int bb = m >> 11, t = m & 2047;
          vt[((size_t)bb * Dq + n) * Tq + t] = s;
        }
      }
    }
  }
}

// Causal flash attention. 1 wave (64 thr) per block, 16 q-rows per wave.
// grid 512 = 4 batches * 128 q-tiles, longest tiles scheduled first.
__global__ __launch_bounds__(64) void attn_kernel(const short* __restrict__ qb,
                                                  const short* __restrict__ kb2,
                                                  const short* __restrict__ vt,
                                                  float* __restrict__ out) {
  __shared__ short pl[16][32];      // wave-private P transpose buffer
  int bid = blockIdx.x;
  int b   = bid & 3;
  int qt  = 127 - (bid >> 2);       // descending work
  int l   = threadIdx.x;
  int r   = l & 15, h = l >> 4;     // frag row / k-chunk; also C/D col / row-group

  bf16x8 aq[4];
  size_t qbase = ((size_t)b * Tq + qt * 16 + r) * Dq;
  #pragma unroll
  for (int kt = 0; kt < 4; ++kt)
    aq[kt] = *reinterpret_cast<const bf16x8*>(qb + qbase + kt * 32 + h * 8);

  f32x4 acc[8] = {};
  float mrun[4], lrun[4];
  #pragma unroll
  for (int i2 = 0; i2 < 4; ++i2) { mrun[i2] = -1e30f; lrun[i2] = 0.0f; }

  int kvend  = qt * 16 + 16;
  int ntiles = (kvend + 31) >> 5;

  for (int it = 0; it < ntiles; ++it) {
    int kv0 = it * 32;
    f32x4 s[2] = {};
    #pragma unroll
    for (int nt = 0; nt < 2; ++nt) {
      size_t krow = ((size_t)b * Tq + kv0 + nt * 16 + r) * Dq;
      #pragma unroll
      for (int kt = 0; kt < 4; ++kt) {
        bf16x8 bk = *reinterpret_cast<const bf16x8*>(kb2 + krow + kt * 32 + h * 8);
        s[nt] = __builtin_amdgcn_mfma_f32_16x16x32_bf16(aq[kt], bk, s[nt], 0, 0, 0);
      }
    }
    if (kv0 + 31 > qt * 16) {           // causal mask only near/past the diagonal
      #pragma unroll
      for (int nt = 0; nt < 2; ++nt)
        #pragma unroll
        for (int reg = 0; reg < 4; ++reg) {
          int colg = kv0 + nt * 16 + r;
          int rowg = qt * 16 + h * 4 + reg;
          if (colg > rowg) s[nt][reg] = -1e30f;
        }
    }
    float mnew[4], alpha[4], p[2][4];
    #pragma unroll
    for (int reg = 0; reg < 4; ++reg) {
      float mx = fmaxf(s[0][reg], s[1][reg]);
      #pragma unroll
      for (int d = 1; d < 16; d <<= 1) mx = fmaxf(mx, __shfl_xor(mx, d));
      mnew[reg]  = fmaxf(mrun[reg], mx);
      alpha[reg] = __expf(mrun[reg] - mnew[reg]);
      mrun[reg]  = mnew[reg];
    }
    #pragma unroll
    for (int reg = 0; reg < 4; ++reg) {
      p[0][reg] = __expf(s[0][reg] - mnew[reg]);
      p[1][reg] = __expf(s[1][reg] - mnew[reg]);
      float sm = p[0][reg] + p[1][reg];
      #pragma unroll
      for (int d = 1; d < 16; d <<= 1) sm += __shfl_xor(sm, d);
      lrun[reg] = lrun[reg] * alpha[reg] + sm;
    }
    #pragma unroll
    for (int dt = 0; dt < 8; ++dt)
      #pragma unroll
      for (int reg = 0; reg < 4; ++reg) acc[dt][reg] *= alpha[reg];

    __syncthreads();                     // WAR: previous ap read
    #pragma unroll
    for (int nt = 0; nt < 2; ++nt)
      #pragma unroll
      for (int reg = 0; reg < 4; ++reg)
        pl[h * 4 + reg][nt * 16 + r] = f2bf(p[nt][reg]);
    __syncthreads();
    bf16x8 ap = *reinterpret_cast<const bf16x8*>(&pl[r][h * 8]);

    #pragma unroll
    for (int dt = 0; dt < 8; ++dt) {
      bf16x8 bv = *reinterpret_cast<const bf16x8*>(
          vt + ((size_t)b * Dq + dt * 16 + r) * Tq + kv0 + h * 8);
      acc[dt] = __builtin_amdgcn_mfma_f32_16x16x32_bf16(ap, bv, acc[dt], 0, 0, 0);
    }
  }
  #pragma unroll
  for (int reg = 0; reg < 4; ++reg) {
    float inv = 1.0f / lrun[reg];
    #pragma unroll
    for (int dt = 0; dt < 8; ++dt)
      out[((size_t)b * Tq + qt * 16 + h * 4 + reg) * Dq + dt * 16 + r] = acc[dt][reg] * inv;
  }
}

extern "C" void kernel_launch(void* const* d_in, const int* in_sizes, int n_in,
                              void* d_out, int out_size, void* d_ws, size_t ws_size,
                              hipStream_t stream) {
  const float* x   = (const float*)d_in[0];
  const float* Wq_ = (const float*)d_in[1];
  const float* Wk_ = (const float*)d_in[2];
  const float* Wv_ = (const float*)d_in[3];
  float* out = (float*)d_out;
  char* ws = (char*)d_ws;
  short* xp = (short*)(ws);               // 16,777,216 B  x packed bf16
  short* wp = (short*)(ws + 16777216);    //    786,432 B  Wq/Wk/Wv packed bf16
  short* qb = (short*)(ws + 17563648);    //  2,097,152 B  q row-major bf16 (pre-scaled)
  short* kb = (short*)(ws + 19660800);    //  2,097,152 B  k row-major bf16
  short* vt = (short*)(ws + 21757952);    //  2,097,152 B  v transposed [b][d][t] bf16

  hipLaunchKernelGGL(pack_x_kernel, dim3(4096), dim3(256), 0, stream, x, xp);
  hipLaunchKernelGGL(pack_w_kernel, dim3(192), dim3(256), 0, stream, Wq_, Wk_, Wv_, wp);
  hipLaunchKernelGGL(qkv_gemm_kernel, dim3(64, 3), dim3(256), 0, stream, xp, wp, qb, kb, vt);
  hipLaunchKernelGGL(attn_kernel, dim3(512), dim3(64), 0, stream, qb, kb, vt, out);
}

// Round 2
// 90.437 us; speedup vs baseline: 1.5071x; 1.5071x over previous
//
#include <hip/hip_runtime.h>
#include <hip/hip_bf16.h>

typedef __attribute__((ext_vector_type(8))) short bf16x8;
typedef __attribute__((ext_vector_type(4))) float f32x4;

#define Bq 4
#define Tq 2048
#define Cq 1024
#define Dq 128
#define KT (Cq/32)   // 32 k-tiles of 32

__device__ __forceinline__ short f2bf(float f) {
  unsigned u = __float_as_uint(f);
  u += 0x7fffu + ((u >> 16) & 1u);   // RNE; inputs are finite
  return (short)(u >> 16);
}

// x [8192][1024] fp32 -> bf16 packed in MFMA A-frag order:
// xp[((mt*KT + kt)*64 + l)*8 + j] = x[mt*16 + l%16][kt*32 + (l/16)*8 + j]
__global__ __launch_bounds__(256) void pack_x_kernel(const float* __restrict__ x,
                                                     short* __restrict__ xp) {
  int tid = blockIdx.x * 256 + threadIdx.x;      // 8192*128 threads
  int row = tid >> 7;
  int k0  = (tid & 127) << 3;
  const float4* src = reinterpret_cast<const float4*>(x + (size_t)row * Cq + k0);
  float4 v0 = src[0];
  float4 v1 = src[1];
  int mt = row >> 4, r = row & 15;
  int kt = k0 >> 5,  h = (k0 >> 3) & 3;
  int l  = h * 16 + r;
  bf16x8 o;
  o[0]=f2bf(v0.x); o[1]=f2bf(v0.y); o[2]=f2bf(v0.z); o[3]=f2bf(v0.w);
  o[4]=f2bf(v1.x); o[5]=f2bf(v1.y); o[6]=f2bf(v1.z); o[7]=f2bf(v1.w);
  reinterpret_cast<bf16x8*>(xp)[((size_t)mt * KT + kt) * 64 + l] = o;
}

// W [1024][128] fp32 -> bf16 packed in MFMA B-frag order (3 matrices);
// D^-0.5 folded into Wq (y==0).
__global__ __launch_bounds__(256) void pack_w_kernel(const float* __restrict__ Wq_,
                                                     const float* __restrict__ Wk_,
                                                     const float* __restrict__ Wv_,
                                                     short* __restrict__ wp) {
  int tid = blockIdx.x * 256 + threadIdx.x;      // 3*16384 threads
  int y   = tid >> 14;
  int idx = tid & 16383;
  int l   = idx & 63;
  const float* W = (y == 0) ? Wq_ : (y == 1 ? Wk_ : Wv_);
  float scale = (y == 0) ? 0.08838834764831845f : 1.0f;   // 1/sqrt(128)
  int kbase = (idx >> 9) * 32 + (l >> 4) * 8;
  int n     = ((idx >> 6) & 7) * 16 + (l & 15);
  bf16x8 o;
  #pragma unroll
  for (int j = 0; j < 8; ++j) o[j] = f2bf(W[(size_t)(kbase + j) * Dq + n] * scale);
  reinterpret_cast<bf16x8*>(wp)[tid] = o;        // == y*16384 + idx
}

// QKV GEMM: grid (128, 3). Block 256 = 4 waves, each wave 32x64 (2x4 frags).
// 1536 waves total (1.5/SIMD) for latency hiding; frags stream from L2/L3.
__global__ __launch_bounds__(256) void qkv_gemm_kernel(const short* __restrict__ xp,
                                                       const short* __restrict__ wp,
                                                       short* __restrict__ qb,
                                                       short* __restrict__ kb2,
                                                       short* __restrict__ vt) {
  int y  = blockIdx.y;
  int bm = blockIdx.x;
  int w  = threadIdx.x >> 6, l = threadIdx.x & 63;
  int wr = w >> 1, wc = w & 1;
  const bf16x8* A8 = reinterpret_cast<const bf16x8*>(xp);
  const bf16x8* B8 = reinterpret_cast<const bf16x8*>(wp) + (size_t)y * 16384;
  f32x4 acc[2][4] = {};
  int mt0 = bm * 4 + wr * 2;
  int nt0 = wc * 4;
  #pragma unroll 2
  for (int kt = 0; kt < KT; ++kt) {
    bf16x8 a[2], b[4];
    #pragma unroll
    for (int mi = 0; mi < 2; ++mi) a[mi] = A8[((size_t)(mt0 + mi) * KT + kt) * 64 + l];
    #pragma unroll
    for (int ni = 0; ni < 4; ++ni) b[ni] = B8[((size_t)kt * 8 + nt0 + ni) * 64 + l];
    #pragma unroll
    for (int mi = 0; mi < 2; ++mi)
      #pragma unroll
      for (int ni = 0; ni < 4; ++ni)
        acc[mi][ni] = __builtin_amdgcn_mfma_f32_16x16x32_bf16(a[mi], b[ni], acc[mi][ni], 0, 0, 0);
  }
  int g = l >> 4, c0 = l & 15;
  #pragma unroll
  for (int mi = 0; mi < 2; ++mi) {
    #pragma unroll
    for (int ni = 0; ni < 4; ++ni) {
      #pragma unroll
      for (int reg = 0; reg < 4; ++reg) {
        int m = bm * 64 + wr * 32 + mi * 16 + g * 4 + reg;
        int n = wc * 64 + ni * 16 + c0;
        short s = f2bf(acc[mi][ni][reg]);
        if (y == 0)      qb[(size_t)m * Dq + n] = s;
        else if (y == 1) kb2[(size_t)m * Dq + n] = s;
        else {
          int bb = m >> 11, t = m & 2047;
          vt[((size_t)bb * Dq + n) * Tq + t] = s;
        }
      }
    }
  }
}

// Causal flash attention, in-block KV split-K.
// 512 blocks x 512 threads (8 waves). Block task = (b, qt) [16 q-rows].
// Wave w processes KV tiles w, w+8, ... with private online-softmax state;
// block-end combine via LDS. XCD mapping: 2 XCDs per batch (K/V L2-resident).
__global__ __launch_bounds__(512, 4) void attn_kernel(const short* __restrict__ qb,
                                                      const short* __restrict__ kb2,
                                                      const short* __restrict__ vt,
                                                      float* __restrict__ out) {
  __shared__ struct {
    short pl[8][2][16][32];      // per-wave ping-pong P buffers (16 KB)
    float cacc[4][16][128];      // combine accumulators (32 KB)
    float lm[8][16];
    float ll[8][16];
  } sm;                          // 50176 B

  int bid  = blockIdx.x;
  int xcd  = bid & 7, slot = bid >> 3;
  int b    = xcd >> 1;                       // XCD pair {2b,2b+1} -> batch b
  int qt   = 127 - (slot * 2 + (xcd & 1));   // long tasks dispatched first
  int tid  = threadIdx.x;
  int w    = tid >> 6, l = tid & 63;
  int r    = l & 15, h = l >> 4;

  bf16x8 aq[4];
  size_t qbase = ((size_t)b * Tq + qt * 16 + r) * Dq;
  #pragma unroll
  for (int kt = 0; kt < 4; ++kt)
    aq[kt] = *reinterpret_cast<const bf16x8*>(qb + qbase + kt * 32 + h * 8);

  f32x4 acc[8] = {};
  float mrun[4], lrun[4];
  #pragma unroll
  for (int i2 = 0; i2 < 4; ++i2) { mrun[i2] = -1e30f; lrun[i2] = 0.0f; }

  int ntiles = (qt >> 1) + 1;                // KV tiles of 32, incl. diagonal
  int pp = 0;

  for (int it = w; it < ntiles; it += 8, pp ^= 1) {
    int kv0 = it * 32;
    f32x4 s[2] = {};
    #pragma unroll
    for (int nt = 0; nt < 2; ++nt) {
      size_t krow = ((size_t)b * Tq + kv0 + nt * 16 + r) * Dq;
      #pragma unroll
      for (int kt = 0; kt < 4; ++kt) {
        bf16x8 bk = *reinterpret_cast<const bf16x8*>(kb2 + krow + kt * 32 + h * 8);
        s[nt] = __builtin_amdgcn_mfma_f32_16x16x32_bf16(aq[kt], bk, s[nt], 0, 0, 0);
      }
    }
    if (kv0 + 31 > qt * 16) {                // causal mask near diagonal
      #pragma unroll
      for (int nt = 0; nt < 2; ++nt)
        #pragma unroll
        for (int reg = 0; reg < 4; ++reg) {
          int colg = kv0 + nt * 16 + r;
          int rowg = qt * 16 + h * 4 + reg;
          if (colg > rowg) s[nt][reg] = -1e30f;
        }
    }
    float mnew[4], alpha[4], p[2][4];
    #pragma unroll
    for (int reg = 0; reg < 4; ++reg) {
      float mx = fmaxf(s[0][reg], s[1][reg]);
      #pragma unroll
      for (int d = 1; d < 16; d <<= 1) mx = fmaxf(mx, __shfl_xor(mx, d));
      mnew[reg]  = fmaxf(mrun[reg], mx);
      alpha[reg] = __expf(mrun[reg] - mnew[reg]);
      mrun[reg]  = mnew[reg];
    }
    #pragma unroll
    for (int reg = 0; reg < 4; ++reg) {
      p[0][reg] = __expf(s[0][reg] - mnew[reg]);
      p[1][reg] = __expf(s[1][reg] - mnew[reg]);
      float sum = p[0][reg] + p[1][reg];
      #pragma unroll
      for (int d = 1; d < 16; d <<= 1) sum += __shfl_xor(sum, d);
      lrun[reg] = lrun[reg] * alpha[reg] + sum;
    }
    #pragma unroll
    for (int dt = 0; dt < 8; ++dt)
      #pragma unroll
      for (int reg = 0; reg < 4; ++reg) acc[dt][reg] *= alpha[reg];

    // P transpose through wave-private ping-pong LDS (no __syncthreads: waves
    // have different trip counts; same-wave DS ordering + explicit lgkmcnt).
    #pragma unroll
    for (int nt = 0; nt < 2; ++nt)
      #pragma unroll
      for (int reg = 0; reg < 4; ++reg)
        sm.pl[w][pp][h * 4 + reg][nt * 16 + r] = f2bf(p[nt][reg]);
    asm volatile("s_waitcnt lgkmcnt(0)" ::: "memory");
    bf16x8 ap = *reinterpret_cast<const bf16x8*>(&sm.pl[w][pp][r][h * 8]);

    #pragma unroll
    for (int dt = 0; dt < 8; ++dt) {
      bf16x8 bv = *reinterpret_cast<const bf16x8*>(
          vt + ((size_t)b * Dq + dt * 16 + r) * Tq + kv0 + h * 8);
      acc[dt] = __builtin_amdgcn_mfma_f32_16x16x32_bf16(ap, bv, acc[dt], 0, 0, 0);
    }
  }

  // ---- block combine ----
  if (r == 0) {
    #pragma unroll
    for (int reg = 0; reg < 4; ++reg) {
      sm.lm[w][h * 4 + reg] = mrun[reg];
      sm.ll[w][h * 4 + reg] = lrun[reg];
    }
  }
  __syncthreads();

  float fac[4];
  #pragma unroll
  for (int reg = 0; reg < 4; ++reg) {
    int row = h * 4 + reg;
    float M = sm.lm[0][row];
    #pragma unroll
    for (int ww = 1; ww < 8; ++ww) M = fmaxf(M, sm.lm[ww][row]);
    float W = 0.0f;
    #pragma unroll
    for (int ww = 0; ww < 8; ++ww) W += __expf(sm.lm[ww][row] - M) * sm.ll[ww][row];
    fac[reg] = __expf(mrun[reg] - M) / W;    // empty wave: exp(-huge)=0
  }
  #pragma unroll
  for (int dt = 0; dt < 8; ++dt)
    #pragma unroll
    for (int reg = 0; reg < 4; ++reg) acc[dt][reg] *= fac[reg];

  if (w < 4) {
    #pragma unroll
    for (int dt = 0; dt < 8; ++dt)
      #pragma unroll
      for (int reg = 0; reg < 4; ++reg)
        sm.cacc[w][h * 4 + reg][dt * 16 + r] = acc[dt][reg];
  }
  __syncthreads();
  if (w >= 4) {
    #pragma unroll
    for (int dt = 0; dt < 8; ++dt)
      #pragma unroll
      for (int reg = 0; reg < 4; ++reg)
        sm.cacc[w - 4][h * 4 + reg][dt * 16 + r] += acc[dt][reg];
  }
  __syncthreads();

  // final sum of 4 buffers + coalesced store (each thread: 1 float4)
  int row = tid >> 5, c4 = (tid & 31) * 4;
  f32x4 o = {};
  #pragma unroll
  for (int i2 = 0; i2 < 4; ++i2)
    o += *reinterpret_cast<const f32x4*>(&sm.cacc[i2][row][c4]);
  *reinterpret_cast<f32x4*>(out + ((size_t)b * Tq + qt * 16 + row) * Dq + c4) = o;
}

extern "C" void kernel_launch(void* const* d_in, const int* in_sizes, int n_in,
                              void* d_out, int out_size, void* d_ws, size_t ws_size,
                              hipStream_t stream) {
  const float* x   = (const float*)d_in[0];
  const float* Wq_ = (const float*)d_in[1];
  const float* Wk_ = (const float*)d_in[2];
  const float* Wv_ = (const float*)d_in[3];
  float* out = (float*)d_out;
  char* ws = (char*)d_ws;
  short* xp = (short*)(ws);               // 16,777,216 B  x packed bf16
  short* wp = (short*)(ws + 16777216);    //    786,432 B  Wq/Wk/Wv packed bf16
  short* qb = (short*)(ws + 17563648);    //  2,097,152 B  q row-major bf16 (pre-scaled)
  short* kb = (short*)(ws + 19660800);    //  2,097,152 B  k row-major bf16
  short* vt = (short*)(ws + 21757952);    //  2,097,152 B  v transposed [b][d][t] bf16

  hipLaunchKernelGGL(pack_x_kernel, dim3(4096), dim3(256), 0, stream, x, xp);
  hipLaunchKernelGGL(pack_w_kernel, dim3(192), dim3(256), 0, stream, Wq_, Wk_, Wv_, wp);
  hipLaunchKernelGGL(qkv_gemm_kernel, dim3(128, 3), dim3(256), 0, stream, xp, wp, qb, kb, vt);
  hipLaunchKernelGGL(attn_kernel, dim3(512), dim3(512), 0, stream, qb, kb, vt, out);
}

// Round 3
// 81.784 us; speedup vs baseline: 1.6666x; 1.1058x over previous
//
#include <hip/hip_runtime.h>
#include <hip/hip_bf16.h>

typedef __attribute__((ext_vector_type(8))) short bf16x8;
typedef __attribute__((ext_vector_type(4))) float f32x4;

#define Tq 2048
#define Cq 1024
#define Dq 128
#define KT 32        // k-tiles of 32 in C dim

__device__ __forceinline__ short f2bf(float f) {
  unsigned u = __float_as_uint(f);
  u += 0x7fffu + ((u >> 16) & 1u);   // RNE; inputs are finite
  return (short)(u >> 16);
}

// x [8192][1024] fp32 -> bf16 packed in MFMA A-frag order.
__global__ __launch_bounds__(256) void pack_x_kernel(const float* __restrict__ x,
                                                     short* __restrict__ xp) {
  int tid = blockIdx.x * 256 + threadIdx.x;      // 8192*128 threads
  int row = tid >> 7;
  int k0  = (tid & 127) << 3;
  const float4* src = reinterpret_cast<const float4*>(x + (size_t)row * Cq + k0);
  float4 v0 = src[0];
  float4 v1 = src[1];
  int mt = row >> 4, r = row & 15;
  int kt = k0 >> 5,  h = (k0 >> 3) & 3;
  int l  = h * 16 + r;
  bf16x8 o;
  o[0]=f2bf(v0.x); o[1]=f2bf(v0.y); o[2]=f2bf(v0.z); o[3]=f2bf(v0.w);
  o[4]=f2bf(v1.x); o[5]=f2bf(v1.y); o[6]=f2bf(v1.z); o[7]=f2bf(v1.w);
  reinterpret_cast<bf16x8*>(xp)[((size_t)mt * KT + kt) * 64 + l] = o;
}

// W [1024][128] fp32 -> bf16 packed in MFMA B-frag order; D^-0.5 folded into Wq.
__global__ __launch_bounds__(256) void pack_w_kernel(const float* __restrict__ Wq_,
                                                     const float* __restrict__ Wk_,
                                                     const float* __restrict__ Wv_,
                                                     short* __restrict__ wp) {
  int tid = blockIdx.x * 256 + threadIdx.x;      // 3*16384 threads
  int y   = tid >> 14;
  int idx = tid & 16383;
  int l   = idx & 63;
  const float* W = (y == 0) ? Wq_ : (y == 1 ? Wk_ : Wv_);
  float scale = (y == 0) ? 0.08838834764831845f : 1.0f;   // 1/sqrt(128)
  int kbase = (idx >> 9) * 32 + (l >> 4) * 8;
  int n     = ((idx >> 6) & 7) * 16 + (l & 15);
  bf16x8 o;
  #pragma unroll
  for (int j = 0; j < 8; ++j) o[j] = f2bf(W[(size_t)(kbase + j) * Dq + n] * scale);
  reinterpret_cast<bf16x8*>(wp)[tid] = o;        // == y*16384 + idx
}

// QKV GEMM: grid (256, 3). Block 256 = 4 waves (2x2), wave tile 32x32.
// Explicit 2-step K staging arrays -> 8 loads in flight per iteration.
__global__ __launch_bounds__(256) void qkv_gemm_kernel(const short* __restrict__ xp,
                                                       const short* __restrict__ wp,
                                                       short* __restrict__ qb,
                                                       short* __restrict__ kb2,
                                                       short* __restrict__ vt) {
  int y  = blockIdx.y;
  int bx = blockIdx.x;
  int bm = bx >> 1, bn = bx & 1;
  int w  = threadIdx.x >> 6, l = threadIdx.x & 63;
  int wr = w >> 1, wc = w & 1;
  const bf16x8* A8 = reinterpret_cast<const bf16x8*>(xp);
  const bf16x8* B8 = reinterpret_cast<const bf16x8*>(wp) + (size_t)y * 16384;
  f32x4 acc[2][2] = {};
  int mt0 = bm * 4 + wr * 2;
  int nt0 = bn * 4 + wc * 2;
  for (int kt = 0; kt < KT; kt += 2) {
    bf16x8 a0[2], b0[2], a1[2], b1[2];
    #pragma unroll
    for (int mi = 0; mi < 2; ++mi) {
      a0[mi] = A8[((size_t)(mt0 + mi) * KT + kt) * 64 + l];
      a1[mi] = A8[((size_t)(mt0 + mi) * KT + kt + 1) * 64 + l];
    }
    #pragma unroll
    for (int ni = 0; ni < 2; ++ni) {
      b0[ni] = B8[((size_t)kt * 8 + nt0 + ni) * 64 + l];
      b1[ni] = B8[((size_t)(kt + 1) * 8 + nt0 + ni) * 64 + l];
    }
    #pragma unroll
    for (int mi = 0; mi < 2; ++mi)
      #pragma unroll
      for (int ni = 0; ni < 2; ++ni)
        acc[mi][ni] = __builtin_amdgcn_mfma_f32_16x16x32_bf16(a0[mi], b0[ni], acc[mi][ni], 0, 0, 0);
    #pragma unroll
    for (int mi = 0; mi < 2; ++mi)
      #pragma unroll
      for (int ni = 0; ni < 2; ++ni)
        acc[mi][ni] = __builtin_amdgcn_mfma_f32_16x16x32_bf16(a1[mi], b1[ni], acc[mi][ni], 0, 0, 0);
  }
  int g = l >> 4, c0 = l & 15;
  #pragma unroll
  for (int mi = 0; mi < 2; ++mi) {
    #pragma unroll
    for (int ni = 0; ni < 2; ++ni) {
      #pragma unroll
      for (int reg = 0; reg < 4; ++reg) {
        int m = bm * 64 + wr * 32 + mi * 16 + g * 4 + reg;
        int n = bn * 64 + wc * 32 + ni * 16 + c0;
        short s = f2bf(acc[mi][ni][reg]);
        if (y == 0)      qb[(size_t)m * Dq + n] = s;
        else if (y == 1) kb2[(size_t)m * Dq + n] = s;
        else {
          int bb = m >> 11, t = m & 2047;
          vt[((size_t)bb * Dq + n) * Tq + t] = s;
        }
      }
    }
  }
}

// Causal flash attention, global split-2 x in-block split-4.
// 1024 blocks x 256 threads (4 waves). bid -> (task b*128+qt, half).
// Wave w handles KV tiles it == half*4+w (mod 8) with private online softmax;
// block writes unnormalized partial (acc, M, L) to workspace.
__global__ __launch_bounds__(256) void attn_kernel(const short* __restrict__ qb,
                                                   const short* __restrict__ kb2,
                                                   const short* __restrict__ vt,
                                                   float* __restrict__ pacc,
                                                   float* __restrict__ pml) {
  __shared__ struct {
    short pl[4][2][16][32];      // per-wave ping-pong P-transpose (8 KB)
    float cacc[2][16][128];      // combine accumulators (16 KB)
    float lm[4][16];
    float ll[4][16];
  } sm;                          // ~25 KB

  int bid  = blockIdx.x;
  int half = bid & 1;
  int tsl  = bid >> 1;                 // 0..511
  int qt   = 127 - (tsl >> 2);         // long tasks first
  int b    = tsl & 3;
  int tid  = threadIdx.x;
  int w    = tid >> 6, l = tid & 63;
  int r    = l & 15, h = l >> 4;

  bf16x8 aq[4];
  size_t qbase = ((size_t)b * Tq + qt * 16 + r) * Dq;
  #pragma unroll
  for (int kt = 0; kt < 4; ++kt)
    aq[kt] = *reinterpret_cast<const bf16x8*>(qb + qbase + kt * 32 + h * 8);

  f32x4 acc[8] = {};
  float mrun[4], lrun[4];
  #pragma unroll
  for (int i2 = 0; i2 < 4; ++i2) { mrun[i2] = -1e30f; lrun[i2] = 0.0f; }

  int ntiles = (qt >> 1) + 1;          // KV tiles of 32, incl. diagonal
  int pp = 0;

  for (int it = half * 4 + w; it < ntiles; it += 8, pp ^= 1) {
    int kv0 = it * 32;
    // stage ALL K frags -> 8 loads in flight
    bf16x8 kf[8];
    #pragma unroll
    for (int nt = 0; nt < 2; ++nt) {
      size_t krow = ((size_t)b * Tq + kv0 + nt * 16 + r) * Dq;
      #pragma unroll
      for (int kt = 0; kt < 4; ++kt)
        kf[nt * 4 + kt] = *reinterpret_cast<const bf16x8*>(kb2 + krow + kt * 32 + h * 8);
    }
    f32x4 s[2] = {};
    #pragma unroll
    for (int nt = 0; nt < 2; ++nt)
      #pragma unroll
      for (int kt = 0; kt < 4; ++kt)
        s[nt] = __builtin_amdgcn_mfma_f32_16x16x32_bf16(aq[kt], kf[nt * 4 + kt], s[nt], 0, 0, 0);

    // issue V loads now; latency hides under softmax (regs reuse dead kf)
    bf16x8 vf[8];
    #pragma unroll
    for (int dt = 0; dt < 8; ++dt)
      vf[dt] = *reinterpret_cast<const bf16x8*>(
          vt + ((size_t)b * Dq + dt * 16 + r) * Tq + kv0 + h * 8);

    if (kv0 + 31 > qt * 16) {          // causal mask near diagonal
      #pragma unroll
      for (int nt = 0; nt < 2; ++nt)
        #pragma unroll
        for (int reg = 0; reg < 4; ++reg) {
          int colg = kv0 + nt * 16 + r;
          int rowg = qt * 16 + h * 4 + reg;
          if (colg > rowg) s[nt][reg] = -1e30f;
        }
    }
    float mnew[4], alpha[4], p[2][4];
    #pragma unroll
    for (int reg = 0; reg < 4; ++reg) {
      float mx = fmaxf(s[0][reg], s[1][reg]);
      #pragma unroll
      for (int d = 1; d < 16; d <<= 1) mx = fmaxf(mx, __shfl_xor(mx, d));
      mnew[reg]  = fmaxf(mrun[reg], mx);
      alpha[reg] = __expf(mrun[reg] - mnew[reg]);
      mrun[reg]  = mnew[reg];
    }
    #pragma unroll
    for (int reg = 0; reg < 4; ++reg) {
      p[0][reg] = __expf(s[0][reg] - mnew[reg]);
      p[1][reg] = __expf(s[1][reg] - mnew[reg]);
      float sum = p[0][reg] + p[1][reg];
      #pragma unroll
      for (int d = 1; d < 16; d <<= 1) sum += __shfl_xor(sum, d);
      lrun[reg] = lrun[reg] * alpha[reg] + sum;
    }
    #pragma unroll
    for (int dt = 0; dt < 8; ++dt)
      #pragma unroll
      for (int reg = 0; reg < 4; ++reg) acc[dt][reg] *= alpha[reg];

    // P transpose through wave-private ping-pong LDS
    #pragma unroll
    for (int nt = 0; nt < 2; ++nt)
      #pragma unroll
      for (int reg = 0; reg < 4; ++reg)
        sm.pl[w][pp][h * 4 + reg][nt * 16 + r] = f2bf(p[nt][reg]);
    asm volatile("s_waitcnt lgkmcnt(0)" ::: "memory");
    bf16x8 ap = *reinterpret_cast<const bf16x8*>(&sm.pl[w][pp][r][h * 8]);

    #pragma unroll
    for (int dt = 0; dt < 8; ++dt)
      acc[dt] = __builtin_amdgcn_mfma_f32_16x16x32_bf16(ap, vf[dt], acc[dt], 0, 0, 0);
  }

  // ---- block combine (4 waves) -> unnormalized partial ----
  if (r == 0) {
    #pragma unroll
    for (int reg = 0; reg < 4; ++reg) {
      sm.lm[w][h * 4 + reg] = mrun[reg];
      sm.ll[w][h * 4 + reg] = lrun[reg];
    }
  }
  __syncthreads();

  float fac[4];
  #pragma unroll
  for (int reg = 0; reg < 4; ++reg) {
    int row = h * 4 + reg;
    float M = sm.lm[0][row];
    #pragma unroll
    for (int ww = 1; ww < 4; ++ww) M = fmaxf(M, sm.lm[ww][row]);
    fac[reg] = __expf(mrun[reg] - M);          // no /W: partial stays unnormalized
    if (w == 0 && r == 0) {
      float L = 0.0f;
      #pragma unroll
      for (int ww = 0; ww < 4; ++ww) L += __expf(sm.lm[ww][row] - M) * sm.ll[ww][row];
      pml[(size_t)bid * 32 + row * 2 + 0] = M;
      pml[(size_t)bid * 32 + row * 2 + 1] = L;
    }
  }
  #pragma unroll
  for (int dt = 0; dt < 8; ++dt)
    #pragma unroll
    for (int reg = 0; reg < 4; ++reg) acc[dt][reg] *= fac[reg];

  if (w < 2) {
    #pragma unroll
    for (int dt = 0; dt < 8; ++dt)
      #pragma unroll
      for (int reg = 0; reg < 4; ++reg)
        sm.cacc[w][h * 4 + reg][dt * 16 + r] = acc[dt][reg];
  }
  __syncthreads();
  if (w >= 2) {
    #pragma unroll
    for (int dt = 0; dt < 8; ++dt)
      #pragma unroll
      for (int reg = 0; reg < 4; ++reg)
        sm.cacc[w - 2][h * 4 + reg][dt * 16 + r] += acc[dt][reg];
  }
  __syncthreads();

  int row = tid >> 4, c8 = (tid & 15) * 8;
  f32x4 o0 = *reinterpret_cast<const f32x4*>(&sm.cacc[0][row][c8]) +
             *reinterpret_cast<const f32x4*>(&sm.cacc[1][row][c8]);
  f32x4 o1 = *reinterpret_cast<const f32x4*>(&sm.cacc[0][row][c8 + 4]) +
             *reinterpret_cast<const f32x4*>(&sm.cacc[1][row][c8 + 4]);
  float* dst = pacc + ((size_t)bid * 16 + row) * 128 + c8;
  *reinterpret_cast<f32x4*>(dst)     = o0;
  *reinterpret_cast<f32x4*>(dst + 4) = o1;
}

// Combine the 2 halves of each task: out = (e0*P0 + e1*P1) / (e0*L0 + e1*L1)
__global__ __launch_bounds__(256) void combine_kernel(const float* __restrict__ pacc,
                                                      const float* __restrict__ pml,
                                                      float* __restrict__ out) {
  int cb = blockIdx.x;                 // 512 tasks, same tsl mapping as attn
  int qt = 127 - (cb >> 2);
  int b  = cb & 3;
  int tid = threadIdx.x;
  int row = tid >> 4, c8 = (tid & 15) * 8;
  int p0 = cb * 2, p1 = cb * 2 + 1;
  float M0 = pml[(size_t)p0 * 32 + row * 2], L0 = pml[(size_t)p0 * 32 + row * 2 + 1];
  float M1 = pml[(size_t)p1 * 32 + row * 2], L1 = pml[(size_t)p1 * 32 + row * 2 + 1];
  float Ms = fmaxf(M0, M1);
  float e0 = __expf(M0 - Ms), e1 = __expf(M1 - Ms);
  float inv = 1.0f / (e0 * L0 + e1 * L1);
  const float* a0 = pacc + ((size_t)p0 * 16 + row) * 128 + c8;
  const float* a1 = pacc + ((size_t)p1 * 16 + row) * 128 + c8;
  f32x4 x0 = *reinterpret_cast<const f32x4*>(a0);
  f32x4 y0 = *reinterpret_cast<const f32x4*>(a1);
  f32x4 x1 = *reinterpret_cast<const f32x4*>(a0 + 4);
  f32x4 y1 = *reinterpret_cast<const f32x4*>(a1 + 4);
  f32x4 o0 = (x0 * e0 + y0 * e1) * inv;
  f32x4 o1 = (x1 * e0 + y1 * e1) * inv;
  float* dst = out + ((size_t)b * Tq + qt * 16 + row) * Dq + c8;
  *reinterpret_cast<f32x4*>(dst)     = o0;
  *reinterpret_cast<f32x4*>(dst + 4) = o1;
}

extern "C" void kernel_launch(void* const* d_in, const int* in_sizes, int n_in,
                              void* d_out, int out_size, void* d_ws, size_t ws_size,
                              hipStream_t stream) {
  const float* x   = (const float*)d_in[0];
  const float* Wq_ = (const float*)d_in[1];
  const float* Wk_ = (const float*)d_in[2];
  const float* Wv_ = (const float*)d_in[3];
  float* out = (float*)d_out;
  char* ws = (char*)d_ws;
  short* xp   = (short*)(ws);               // 16,777,216 B
  short* wp   = (short*)(ws + 16777216);    //    786,432 B
  short* qb   = (short*)(ws + 17563648);    //  2,097,152 B
  short* kb   = (short*)(ws + 19660800);    //  2,097,152 B
  short* vt   = (short*)(ws + 21757952);    //  2,097,152 B
  float* pacc = (float*)(ws + 23855104);    //  8,388,608 B
  float* pml  = (float*)(ws + 32243712);    //    131,072 B  (total ~32.4 MB)

  hipLaunchKernelGGL(pack_x_kernel, dim3(4096), dim3(256), 0, stream, x, xp);
  hipLaunchKernelGGL(pack_w_kernel, dim3(192), dim3(256), 0, stream, Wq_, Wk_, Wv_, wp);
  hipLaunchKernelGGL(qkv_gemm_kernel, dim3(256, 3), dim3(256), 0, stream, xp, wp, qb, kb, vt);
  hipLaunchKernelGGL(attn_kernel, dim3(1024), dim3(256), 0, stream, qb, kb, vt, pacc, pml);
  hipLaunchKernelGGL(combine_kernel, dim3(512), dim3(256), 0, stream, pacc, pml, out);
}

// Round 4
// 79.951 us; speedup vs baseline: 1.7048x; 1.0229x over previous
//
#include <hip/hip_runtime.h>
#include <hip/hip_bf16.h>

typedef __attribute__((ext_vector_type(8))) short bf16x8;
typedef __attribute__((ext_vector_type(4))) short bf16x4;
typedef __attribute__((ext_vector_type(4))) float f32x4;

#define Tq 2048
#define Cq 1024
#define Dq 128
#define KT 32        // k-tiles of 32 in C dim

__device__ __forceinline__ short f2bf(float f) {
  unsigned u = __float_as_uint(f);
  u += 0x7fffu + ((u >> 16) & 1u);   // RNE; inputs are finite
  return (short)(u >> 16);
}

// x [8192][1024] fp32 -> bf16 packed in MFMA A-frag order.
__global__ __launch_bounds__(256) void pack_x_kernel(const float* __restrict__ x,
                                                     short* __restrict__ xp) {
  int tid = blockIdx.x * 256 + threadIdx.x;      // 8192*128 threads
  int row = tid >> 7;
  int k0  = (tid & 127) << 3;
  const float4* src = reinterpret_cast<const float4*>(x + (size_t)row * Cq + k0);
  float4 v0 = src[0];
  float4 v1 = src[1];
  int mt = row >> 4, r = row & 15;
  int kt = k0 >> 5,  h = (k0 >> 3) & 3;
  int l  = h * 16 + r;
  bf16x8 o;
  o[0]=f2bf(v0.x); o[1]=f2bf(v0.y); o[2]=f2bf(v0.z); o[3]=f2bf(v0.w);
  o[4]=f2bf(v1.x); o[5]=f2bf(v1.y); o[6]=f2bf(v1.z); o[7]=f2bf(v1.w);
  reinterpret_cast<bf16x8*>(xp)[((size_t)mt * KT + kt) * 64 + l] = o;
}

// W [1024][128] fp32 -> bf16 packed in MFMA B-frag order; D^-0.5 folded into Wq.
__global__ __launch_bounds__(256) void pack_w_kernel(const float* __restrict__ Wq_,
                                                     const float* __restrict__ Wk_,
                                                     const float* __restrict__ Wv_,
                                                     short* __restrict__ wp) {
  int tid = blockIdx.x * 256 + threadIdx.x;      // 3*16384 threads
  int y   = tid >> 14;
  int idx = tid & 16383;
  int l   = idx & 63;
  const float* W = (y == 0) ? Wq_ : (y == 1 ? Wk_ : Wv_);
  float scale = (y == 0) ? 0.08838834764831845f : 1.0f;   // 1/sqrt(128)
  int kbase = (idx >> 9) * 32 + (l >> 4) * 8;
  int n     = ((idx >> 6) & 7) * 16 + (l & 15);
  bf16x8 o;
  #pragma unroll
  for (int j = 0; j < 8; ++j) o[j] = f2bf(W[(size_t)(kbase + j) * Dq + n] * scale);
  reinterpret_cast<bf16x8*>(wp)[tid] = o;        // == y*16384 + idx
}

// QKV GEMM: grid (256, 3). Block 256 = 4 waves (2x2), wave tile 32x32.
// Unroll-4 staging: 16 loads in flight, no barriers -> compiler pipelines.
__global__ __launch_bounds__(256) void qkv_gemm_kernel(const short* __restrict__ xp,
                                                       const short* __restrict__ wp,
                                                       short* __restrict__ qb,
                                                       short* __restrict__ kb2,
                                                       short* __restrict__ vt) {
  int y  = blockIdx.y;
  int bx = blockIdx.x;
  int bm = bx >> 1, bn = bx & 1;
  int w  = threadIdx.x >> 6, l = threadIdx.x & 63;
  int wr = w >> 1, wc = w & 1;
  const bf16x8* A8 = reinterpret_cast<const bf16x8*>(xp);
  const bf16x8* B8 = reinterpret_cast<const bf16x8*>(wp) + (size_t)y * 16384;
  f32x4 acc[2][2] = {};
  int mt0 = bm * 4 + wr * 2;
  int nt0 = bn * 4 + wc * 2;
  for (int kt = 0; kt < KT; kt += 4) {
    bf16x8 a[4][2], b[4][2];
    #pragma unroll
    for (int u = 0; u < 4; ++u) {
      #pragma unroll
      for (int mi = 0; mi < 2; ++mi)
        a[u][mi] = A8[((size_t)(mt0 + mi) * KT + kt + u) * 64 + l];
      #pragma unroll
      for (int ni = 0; ni < 2; ++ni)
        b[u][ni] = B8[((size_t)(kt + u) * 8 + nt0 + ni) * 64 + l];
    }
    #pragma unroll
    for (int u = 0; u < 4; ++u)
      #pragma unroll
      for (int mi = 0; mi < 2; ++mi)
        #pragma unroll
        for (int ni = 0; ni < 2; ++ni)
          acc[mi][ni] = __builtin_amdgcn_mfma_f32_16x16x32_bf16(a[u][mi], b[u][ni], acc[mi][ni], 0, 0, 0);
  }
  int g = l >> 4, c0 = l & 15;
  #pragma unroll
  for (int mi = 0; mi < 2; ++mi) {
    #pragma unroll
    for (int ni = 0; ni < 2; ++ni) {
      #pragma unroll
      for (int reg = 0; reg < 4; ++reg) {
        int m = bm * 64 + wr * 32 + mi * 16 + g * 4 + reg;
        int n = bn * 64 + wc * 32 + ni * 16 + c0;
        short s = f2bf(acc[mi][ni][reg]);
        if (y == 0)      qb[(size_t)m * Dq + n] = s;
        else if (y == 1) kb2[(size_t)m * Dq + n] = s;
        else {
          int bb = m >> 11, t = m & 2047;
          vt[((size_t)bb * Dq + n) * Tq + t] = s;
        }
      }
    }
  }
}

// Causal flash attention, global split-2 x in-block split-4.
// SWAPPED QK^T: s = mfma(K, Q) -> lane (q=r, h) holds S[q][kv=h*4+reg (+16nt)];
// softmax reduce = 7 local ops + 2 shuffles. K prefetch-rotated in registers.
__global__ __launch_bounds__(256) void attn_kernel(const short* __restrict__ qb,
                                                   const short* __restrict__ kb2,
                                                   const short* __restrict__ vt,
                                                   float* __restrict__ pacc,
                                                   float* __restrict__ pml) {
  __shared__ struct {
    short pl[4][2][16][40];      // per-wave ping-pong P-transpose, 80B rows (10 KB)
    float cacc[2][16][128];      // combine accumulators (16 KB)
    float lm[4][16];
    float ll[4][16];
  } sm;                          // ~27 KB

  int bid  = blockIdx.x;
  int half = bid & 1;
  int tsl  = bid >> 1;                 // 0..511
  int qt   = 127 - (tsl >> 2);         // long tasks first
  int b    = tsl & 3;                  // XCD pair per batch (bid%8 -> b = (bid>>1)&3)
  int tid  = threadIdx.x;
  int w    = tid >> 6, l = tid & 63;
  int r    = l & 15, h = l >> 4;

  // Q fragment (usable as MFMA B-operand: B[k=(l>>4)*8+j][n=l&15] = Q[q=r][d])
  bf16x8 aq[4];
  size_t qbase = ((size_t)b * Tq + qt * 16 + r) * Dq;
  #pragma unroll
  for (int kt = 0; kt < 4; ++kt)
    aq[kt] = *reinterpret_cast<const bf16x8*>(qb + qbase + kt * 32 + h * 8);

  f32x4 acc[8] = {};
  float mrun = -1e30f, lrun = 0.0f;    // per-lane: one q-row (q = qt*16 + r)

  int ntiles = (qt >> 1) + 1;          // KV tiles of 32, incl. diagonal
  int pp = 0;
  int it = half * 4 + w;

  bf16x8 kf[8];
  if (it < ntiles) {                   // initial K stage
    int kv0 = it * 32;
    #pragma unroll
    for (int nt = 0; nt < 2; ++nt) {
      size_t krow = ((size_t)b * Tq + kv0 + nt * 16 + r) * Dq;
      #pragma unroll
      for (int kt = 0; kt < 4; ++kt)
        kf[nt * 4 + kt] = *reinterpret_cast<const bf16x8*>(kb2 + krow + kt * 32 + h * 8);
    }
  }

  for (; it < ntiles; it += 8, pp ^= 1) {
    int kv0 = it * 32;
    // S^T tile: A = K (16kv x 32d), B = Q^T -> C[kv][q]
    f32x4 s[2] = {};
    #pragma unroll
    for (int nt = 0; nt < 2; ++nt)
      #pragma unroll
      for (int kt = 0; kt < 4; ++kt)
        s[nt] = __builtin_amdgcn_mfma_f32_16x16x32_bf16(kf[nt * 4 + kt], aq[kt], s[nt], 0, 0, 0);
    __builtin_amdgcn_sched_barrier(0);  // pin: kf reads above, kf overwrites below

    // V loads for this tile (consumed after softmax)
    bf16x8 vf[8];
    #pragma unroll
    for (int dt = 0; dt < 8; ++dt)
      vf[dt] = *reinterpret_cast<const bf16x8*>(
          vt + ((size_t)b * Dq + dt * 16 + r) * Tq + kv0 + h * 8);

    // K prefetch for it+8 into the same registers (rotation)
    int itn = it + 8;
    if (itn < ntiles) {
      int kvn = itn * 32;
      #pragma unroll
      for (int nt = 0; nt < 2; ++nt) {
        size_t krow = ((size_t)b * Tq + kvn + nt * 16 + r) * Dq;
        #pragma unroll
        for (int kt = 0; kt < 4; ++kt)
          kf[nt * 4 + kt] = *reinterpret_cast<const bf16x8*>(kb2 + krow + kt * 32 + h * 8);
      }
    }

    if (kv0 + 31 > qt * 16) {          // causal mask near diagonal (kv > q)
      #pragma unroll
      for (int nt = 0; nt < 2; ++nt)
        #pragma unroll
        for (int reg = 0; reg < 4; ++reg)
          if (kv0 + nt * 16 + h * 4 + reg > qt * 16 + r) s[nt][reg] = -1e30f;
    }

    // lane-local softmax: 8 values for one q-row + 2 cross-h shuffles
    float mx = fmaxf(fmaxf(fmaxf(s[0][0], s[0][1]), fmaxf(s[0][2], s[0][3])),
                     fmaxf(fmaxf(s[1][0], s[1][1]), fmaxf(s[1][2], s[1][3])));
    mx = fmaxf(mx, __shfl_xor(mx, 16));
    mx = fmaxf(mx, __shfl_xor(mx, 32));
    float mnew  = fmaxf(mrun, mx);
    float alpha = __expf(mrun - mnew);
    mrun = mnew;
    float p[2][4];
    #pragma unroll
    for (int nt = 0; nt < 2; ++nt)
      #pragma unroll
      for (int reg = 0; reg < 4; ++reg) p[nt][reg] = __expf(s[nt][reg] - mnew);
    float rsum = ((p[0][0] + p[0][1]) + (p[0][2] + p[0][3])) +
                 ((p[1][0] + p[1][1]) + (p[1][2] + p[1][3]));
    rsum += __shfl_xor(rsum, 16);
    rsum += __shfl_xor(rsum, 32);
    lrun = lrun * alpha + rsum;

    // broadcast alpha to the accumulator's q-rows (acc row q = h*4+reg)
    float af[4];
    #pragma unroll
    for (int reg = 0; reg < 4; ++reg) af[reg] = __shfl(alpha, h * 4 + reg);
    #pragma unroll
    for (int dt = 0; dt < 8; ++dt)
      #pragma unroll
      for (int reg = 0; reg < 4; ++reg) acc[dt][reg] *= af[reg];

    // P^T[kv][q] -> P[q][kv] via LDS: two b64 writes, one aligned b128 read
    #pragma unroll
    for (int nt = 0; nt < 2; ++nt) {
      bf16x4 w4;
      #pragma unroll
      for (int reg = 0; reg < 4; ++reg) w4[reg] = f2bf(p[nt][reg]);
      *reinterpret_cast<bf16x4*>(&sm.pl[w][pp][r][nt * 16 + h * 4]) = w4;
    }
    asm volatile("s_waitcnt lgkmcnt(0)" ::: "memory");
    __builtin_amdgcn_sched_barrier(0);
    bf16x8 ap = *reinterpret_cast<const bf16x8*>(&sm.pl[w][pp][r][h * 8]);

    #pragma unroll
    for (int dt = 0; dt < 8; ++dt)
      acc[dt] = __builtin_amdgcn_mfma_f32_16x16x32_bf16(ap, vf[dt], acc[dt], 0, 0, 0);
  }

  // ---- block combine (4 waves) -> unnormalized partial ----
  if (h == 0) { sm.lm[w][r] = mrun; sm.ll[w][r] = lrun; }
  __syncthreads();

  float fac[4];
  #pragma unroll
  for (int reg = 0; reg < 4; ++reg) {
    int row = h * 4 + reg;
    float M = sm.lm[0][row];
    #pragma unroll
    for (int ww = 1; ww < 4; ++ww) M = fmaxf(M, sm.lm[ww][row]);
    fac[reg] = __expf(sm.lm[w][row] - M);    // empty wave: exp(-huge)=0
  }
  if (w == 0 && h == 0) {                    // lanes 0..15: one q-row each
    float Mr = sm.lm[0][r];
    #pragma unroll
    for (int ww = 1; ww < 4; ++ww) Mr = fmaxf(Mr, sm.lm[ww][r]);
    float L = 0.0f;
    #pragma unroll
    for (int ww = 0; ww < 4; ++ww) L += __expf(sm.lm[ww][r] - Mr) * sm.ll[ww][r];
    pml[(size_t)bid * 32 + r * 2 + 0] = Mr;
    pml[(size_t)bid * 32 + r * 2 + 1] = L;
  }
  #pragma unroll
  for (int dt = 0; dt < 8; ++dt)
    #pragma unroll
    for (int reg = 0; reg < 4; ++reg) acc[dt][reg] *= fac[reg];

  if (w < 2) {
    #pragma unroll
    for (int dt = 0; dt < 8; ++dt)
      #pragma unroll
      for (int reg = 0; reg < 4; ++reg)
        sm.cacc[w][h * 4 + reg][dt * 16 + r] = acc[dt][reg];
  }
  __syncthreads();
  if (w >= 2) {
    #pragma unroll
    for (int dt = 0; dt < 8; ++dt)
      #pragma unroll
      for (int reg = 0; reg < 4; ++reg)
        sm.cacc[w - 2][h * 4 + reg][dt * 16 + r] += acc[dt][reg];
  }
  __syncthreads();

  int row = tid >> 4, c8 = (tid & 15) * 8;
  f32x4 o0 = *reinterpret_cast<const f32x4*>(&sm.cacc[0][row][c8]) +
             *reinterpret_cast<const f32x4*>(&sm.cacc[1][row][c8]);
  f32x4 o1 = *reinterpret_cast<const f32x4*>(&sm.cacc[0][row][c8 + 4]) +
             *reinterpret_cast<const f32x4*>(&sm.cacc[1][row][c8 + 4]);
  float* dst = pacc + ((size_t)bid * 16 + row) * 128 + c8;
  *reinterpret_cast<f32x4*>(dst)     = o0;
  *reinterpret_cast<f32x4*>(dst + 4) = o1;
}

// Combine the 2 halves of each task: out = (e0*P0 + e1*P1) / (e0*L0 + e1*L1)
__global__ __launch_bounds__(256) void combine_kernel(const float* __restrict__ pacc,
                                                      const float* __restrict__ pml,
                                                      float* __restrict__ out) {
  int cb = blockIdx.x;                 // 512 tasks, same tsl mapping as attn
  int qt = 127 - (cb >> 2);
  int b  = cb & 3;
  int tid = threadIdx.x;
  int row = tid >> 4, c8 = (tid & 15) * 8;
  int p0 = cb * 2, p1 = cb * 2 + 1;
  float M0 = pml[(size_t)p0 * 32 + row * 2], L0 = pml[(size_t)p0 * 32 + row * 2 + 1];
  float M1 = pml[(size_t)p1 * 32 + row * 2], L1 = pml[(size_t)p1 * 32 + row * 2 + 1];
  float Ms = fmaxf(M0, M1);
  float e0 = __expf(M0 - Ms), e1 = __expf(M1 - Ms);
  float inv = 1.0f / (e0 * L0 + e1 * L1);
  const float* a0 = pacc + ((size_t)p0 * 16 + row) * 128 + c8;
  const float* a1 = pacc + ((size_t)p1 * 16 + row) * 128 + c8;
  f32x4 x0 = *reinterpret_cast<const f32x4*>(a0);
  f32x4 y0 = *reinterpret_cast<const f32x4*>(a1);
  f32x4 x1 = *reinterpret_cast<const f32x4*>(a0 + 4);
  f32x4 y1 = *reinterpret_cast<const f32x4*>(a1 + 4);
  f32x4 o0 = (x0 * e0 + y0 * e1) * inv;
  f32x4 o1 = (x1 * e0 + y1 * e1) * inv;
  float* dst = out + ((size_t)b * Tq + qt * 16 + row) * Dq + c8;
  *reinterpret_cast<f32x4*>(dst)     = o0;
  *reinterpret_cast<f32x4*>(dst + 4) = o1;
}

extern "C" void kernel_launch(void* const* d_in, const int* in_sizes, int n_in,
                              void* d_out, int out_size, void* d_ws, size_t ws_size,
                              hipStream_t stream) {
  const float* x   = (const float*)d_in[0];
  const float* Wq_ = (const float*)d_in[1];
  const float* Wk_ = (const float*)d_in[2];
  const float* Wv_ = (const float*)d_in[3];
  float* out = (float*)d_out;
  char* ws = (char*)d_ws;
  short* xp   = (short*)(ws);               // 16,777,216 B
  short* wp   = (short*)(ws + 16777216);    //    786,432 B
  short* qb   = (short*)(ws + 17563648);    //  2,097,152 B
  short* kb   = (short*)(ws + 19660800);    //  2,097,152 B
  short* vt   = (short*)(ws + 21757952);    //  2,097,152 B
  float* pacc = (float*)(ws + 23855104);    //  8,388,608 B
  float* pml  = (float*)(ws + 32243712);    //    131,072 B  (total ~32.4 MB)

  hipLaunchKernelGGL(pack_x_kernel, dim3(4096), dim3(256), 0, stream, x, xp);
  hipLaunchKernelGGL(pack_w_kernel, dim3(192), dim3(256), 0, stream, Wq_, Wk_, Wv_, wp);
  hipLaunchKernelGGL(qkv_gemm_kernel, dim3(256, 3), dim3(256), 0, stream, xp, wp, qb, kb, vt);
  hipLaunchKernelGGL(attn_kernel, dim3(1024), dim3(256), 0, stream, qb, kb, vt, pacc, pml);
  hipLaunchKernelGGL(combine_kernel, dim3(512), dim3(256), 0, stream, pacc, pml, out);
}

// Round 5
// 73.619 us; speedup vs baseline: 1.8514x; 1.0860x over previous
//
#include <hip/hip_runtime.h>
#include <hip/hip_bf16.h>

typedef __attribute__((ext_vector_type(8))) short bf16x8;
typedef __attribute__((ext_vector_type(4))) short bf16x4;
typedef __attribute__((ext_vector_type(4))) float f32x4;

#define Tq 2048
#define Cq 1024
#define Dq 128
#define KT 32        // k-tiles of 32 in C dim

typedef const __attribute__((address_space(1))) void* gas_t;
typedef __attribute__((address_space(3))) void* las_t;

__device__ __forceinline__ short f2bf(float f) {
  unsigned u = __float_as_uint(f);
  u += 0x7fffu + ((u >> 16) & 1u);   // RNE; inputs are finite
  return (short)(u >> 16);
}

// x [8192][1024] fp32 -> bf16 packed in MFMA A-frag order.
__global__ __launch_bounds__(256) void pack_x_kernel(const float* __restrict__ x,
                                                     short* __restrict__ xp) {
  int tid = blockIdx.x * 256 + threadIdx.x;      // 8192*128 threads
  int row = tid >> 7;
  int k0  = (tid & 127) << 3;
  const float4* src = reinterpret_cast<const float4*>(x + (size_t)row * Cq + k0);
  float4 v0 = src[0];
  float4 v1 = src[1];
  int mt = row >> 4, r = row & 15;
  int kt = k0 >> 5,  h = (k0 >> 3) & 3;
  int l  = h * 16 + r;
  bf16x8 o;
  o[0]=f2bf(v0.x); o[1]=f2bf(v0.y); o[2]=f2bf(v0.z); o[3]=f2bf(v0.w);
  o[4]=f2bf(v1.x); o[5]=f2bf(v1.y); o[6]=f2bf(v1.z); o[7]=f2bf(v1.w);
  reinterpret_cast<bf16x8*>(xp)[((size_t)mt * KT + kt) * 64 + l] = o;
}

// W [1024][128] fp32 -> bf16 packed in MFMA B-frag order; D^-0.5 folded into Wq.
__global__ __launch_bounds__(256) void pack_w_kernel(const float* __restrict__ Wq_,
                                                     const float* __restrict__ Wk_,
                                                     const float* __restrict__ Wv_,
                                                     short* __restrict__ wp) {
  int tid = blockIdx.x * 256 + threadIdx.x;      // 3*16384 threads
  int y   = tid >> 14;
  int idx = tid & 16383;
  int l   = idx & 63;
  const float* W = (y == 0) ? Wq_ : (y == 1 ? Wk_ : Wv_);
  float scale = (y == 0) ? 0.08838834764831845f : 1.0f;   // 1/sqrt(128)
  int kbase = (idx >> 9) * 32 + (l >> 4) * 8;
  int n     = ((idx >> 6) & 7) * 16 + (l & 15);
  bf16x8 o;
  #pragma unroll
  for (int j = 0; j < 8; ++j) o[j] = f2bf(W[(size_t)(kbase + j) * Dq + n] * scale);
  reinterpret_cast<bf16x8*>(wp)[tid] = o;        // == y*16384 + idx
}

// QKV GEMM: grid (256, 3). Block 256 = 4 waves (2x2), wave tile 32x32.
__global__ __launch_bounds__(256) void qkv_gemm_kernel(const short* __restrict__ xp,
                                                       const short* __restrict__ wp,
                                                       short* __restrict__ qb,
                                                       short* __restrict__ kb2,
                                                       short* __restrict__ vt) {
  int y  = blockIdx.y;
  int bx = blockIdx.x;
  int bm = bx >> 1, bn = bx & 1;
  int w  = threadIdx.x >> 6, l = threadIdx.x & 63;
  int wr = w >> 1, wc = w & 1;
  const bf16x8* A8 = reinterpret_cast<const bf16x8*>(xp);
  const bf16x8* B8 = reinterpret_cast<const bf16x8*>(wp) + (size_t)y * 16384;
  f32x4 acc[2][2] = {};
  int mt0 = bm * 4 + wr * 2;
  int nt0 = bn * 4 + wc * 2;
  for (int kt = 0; kt < KT; kt += 4) {
    bf16x8 a[4][2], b[4][2];
    #pragma unroll
    for (int u = 0; u < 4; ++u) {
      #pragma unroll
      for (int mi = 0; mi < 2; ++mi)
        a[u][mi] = A8[((size_t)(mt0 + mi) * KT + kt + u) * 64 + l];
      #pragma unroll
      for (int ni = 0; ni < 2; ++ni)
        b[u][ni] = B8[((size_t)(kt + u) * 8 + nt0 + ni) * 64 + l];
    }
    #pragma unroll
    for (int u = 0; u < 4; ++u)
      #pragma unroll
      for (int mi = 0; mi < 2; ++mi)
        #pragma unroll
        for (int ni = 0; ni < 2; ++ni)
          acc[mi][ni] = __builtin_amdgcn_mfma_f32_16x16x32_bf16(a[u][mi], b[u][ni], acc[mi][ni], 0, 0, 0);
  }
  int g = l >> 4, c0 = l & 15;
  #pragma unroll
  for (int mi = 0; mi < 2; ++mi) {
    #pragma unroll
    for (int ni = 0; ni < 2; ++ni) {
      #pragma unroll
      for (int reg = 0; reg < 4; ++reg) {
        int m = bm * 64 + wr * 32 + mi * 16 + g * 4 + reg;
        int n = bn * 64 + wc * 32 + ni * 16 + c0;
        short s = f2bf(acc[mi][ni][reg]);
        if (y == 0)      qb[(size_t)m * Dq + n] = s;
        else if (y == 1) kb2[(size_t)m * Dq + n] = s;
        else {
          int bb = m >> 11, t = m & 2047;
          vt[((size_t)bb * Dq + n) * Tq + t] = s;
        }
      }
    }
  }
}

// Causal flash attention with LDS-staged K/V via global_load_lds (async DMA).
// 512 blocks x 128 thr (2 waves). bid -> (qi64-tile, batch, kv-chunk c of 4).
// Wave w owns 32 q-rows (2 subtiles of 16). Double-buffered LDS, counted
// vmcnt(8), raw s_barrier (no vmcnt(0) drain). XOR-swizzled staging (src-side).
__global__ __launch_bounds__(128) void attn_kernel(const short* __restrict__ qb,
                                                   const short* __restrict__ kb2,
                                                   const short* __restrict__ vtb,
                                                   float* __restrict__ pacc,
                                                   float* __restrict__ pml) {
  __shared__ struct {
    short kb[2][32][128];       // K tile, rows swizzled: [row][c ^ ((row&7)<<3)]
    short vb[2][128][32];       // V^T tile: [d-row][kv ^ ((row&3)<<3)]
    short pb[2][2][16][40];     // per-wave per-subtile P transpose (padded)
  } sm;                         // 37,888 B -> 4 blocks/CU

  int bid = blockIdx.x;
  int qi  = 31 - (bid >> 4);           // long tasks dispatched first
  int b   = (bid >> 2) & 3;
  int c   = bid & 3;
  int tid = threadIdx.x;
  int w   = tid >> 6, l = tid & 63;
  int r   = l & 15, h = l >> 4;

  int q0 = qi * 64;
  int qw = q0 + w * 32;                // wave's first q row
  const short* kbB = kb2 + (size_t)b * Tq * Dq;
  const short* vtB = vtb + (size_t)b * Dq * Tq;

  // Q frags (B-operand layout): subtile j rows [qw+j*16, +16)
  bf16x8 aq[2][4];
  #pragma unroll
  for (int j = 0; j < 2; ++j) {
    size_t qbase = ((size_t)b * Tq + qw + j * 16 + r) * Dq;
    #pragma unroll
    for (int kt = 0; kt < 4; ++kt)
      aq[j][kt] = *reinterpret_cast<const bf16x8*>(qb + qbase + kt * 32 + h * 8);
  }

  int ntall = 2 * qi + 2;              // kv tiles of 32 covering [0, q0+64)
  int clen  = (ntall + 3) >> 2;
  int tbeg  = c * clen;
  int tend  = ntall < tbeg + clen ? ntall : tbeg + clen;

  f32x4 acc[2][8] = {};
  float mrun[2] = {-1e30f, -1e30f}, lrun[2] = {0.0f, 0.0f};

  if (tbeg < tend) {
    auto stage = [&](int it, int bi) {
      int kv0 = it * 32;
      #pragma unroll
      for (int i2 = 0; i2 < 4; ++i2) {          // K: 1 KB per inst
        int i = w * 4 + i2;
        int row = i * 4 + (l >> 4);
        int sc  = ((l & 15) * 8) ^ ((row & 7) << 3);
        __builtin_amdgcn_global_load_lds(
            (gas_t)(kbB + (size_t)(kv0 + row) * Dq + sc),
            (las_t)(&sm.kb[bi][i * 4][0]), 16, 0, 0);
      }
      #pragma unroll
      for (int i2 = 0; i2 < 4; ++i2) {          // V: 1 KB per inst
        int i = w * 4 + i2;
        int row = i * 16 + (l >> 2);
        int sc  = ((l & 3) * 8) ^ ((row & 3) << 3);
        __builtin_amdgcn_global_load_lds(
            (gas_t)(vtB + (size_t)row * Tq + kv0 + sc),
            (las_t)(&sm.vb[bi][i * 16][0]), 16, 0, 0);
      }
    };

    stage(tbeg, 0);
    int cur = 0;
    for (int t = tbeg; t < tend; ++t, cur ^= 1) {
      int pf = (t + 1 < tend) ? t + 1 : t;      // always issue 8 (vmcnt math)
      stage(pf, cur ^ 1);
      asm volatile("s_waitcnt vmcnt(8)" ::: "memory");  // cur's loads landed (mine)
      __builtin_amdgcn_s_barrier();                      // ...and the other wave's
      __builtin_amdgcn_sched_barrier(0);

      int kv0 = t * 32;
      // K frags from LDS (shared across both subtiles)
      bf16x8 kf[8];
      #pragma unroll
      for (int nt = 0; nt < 2; ++nt)
        #pragma unroll
        for (int kt = 0; kt < 4; ++kt) {
          int row = nt * 16 + r;
          kf[nt * 4 + kt] = *reinterpret_cast<const bf16x8*>(
              &sm.kb[cur][row][(kt * 32 + h * 8) ^ ((row & 7) << 3)]);
        }
      f32x4 s[2][2] = {};
      #pragma unroll
      for (int j = 0; j < 2; ++j)
        #pragma unroll
        for (int nt = 0; nt < 2; ++nt)
          #pragma unroll
          for (int kt = 0; kt < 4; ++kt)
            s[j][nt] = __builtin_amdgcn_mfma_f32_16x16x32_bf16(
                kf[nt * 4 + kt], aq[j][kt], s[j][nt], 0, 0, 0);

      // V frags (ds_reads overlap softmax below)
      bf16x8 vf[8];
      #pragma unroll
      for (int dt = 0; dt < 8; ++dt) {
        int row = dt * 16 + r;
        vf[dt] = *reinterpret_cast<const bf16x8*>(
            &sm.vb[cur][row][(h * 8) ^ ((row & 3) << 3)]);
      }

      // causal mask (kv > q); per-lane q = (qw + j*16) + r, kv = kv0+nt*16+h*4+reg
      #pragma unroll
      for (int j = 0; j < 2; ++j) {
        int qb_j = qw + j * 16;
        if (kv0 + 31 > qb_j) {
          #pragma unroll
          for (int nt = 0; nt < 2; ++nt)
            #pragma unroll
            for (int reg = 0; reg < 4; ++reg)
              if (kv0 + nt * 16 + h * 4 + reg > qb_j + r) s[j][nt][reg] = -1e30f;
        }
      }

      // two independent per-subtile softmax chains (compiler interleaves)
      bf16x8 ap[2];
      #pragma unroll
      for (int j = 0; j < 2; ++j) {
        float mx = fmaxf(fmaxf(fmaxf(s[j][0][0], s[j][0][1]), fmaxf(s[j][0][2], s[j][0][3])),
                         fmaxf(fmaxf(s[j][1][0], s[j][1][1]), fmaxf(s[j][1][2], s[j][1][3])));
        mx = fmaxf(mx, __shfl_xor(mx, 16));
        mx = fmaxf(mx, __shfl_xor(mx, 32));
        float mnew  = fmaxf(mrun[j], mx);
        float alpha = __expf(mrun[j] - mnew);
        mrun[j] = mnew;
        float p[2][4];
        #pragma unroll
        for (int nt = 0; nt < 2; ++nt)
          #pragma unroll
          for (int reg = 0; reg < 4; ++reg)
            p[nt][reg] = s[j][nt][reg] > -1e29f ? __expf(s[j][nt][reg] - mnew) : 0.0f;
        float rsum = ((p[0][0] + p[0][1]) + (p[0][2] + p[0][3])) +
                     ((p[1][0] + p[1][1]) + (p[1][2] + p[1][3]));
        rsum += __shfl_xor(rsum, 16);
        rsum += __shfl_xor(rsum, 32);
        lrun[j] = lrun[j] * alpha + rsum;

        float af[4];
        #pragma unroll
        for (int reg = 0; reg < 4; ++reg) af[reg] = __shfl(alpha, h * 4 + reg);
        #pragma unroll
        for (int dt = 0; dt < 8; ++dt)
          #pragma unroll
          for (int reg = 0; reg < 4; ++reg) acc[j][dt][reg] *= af[reg];

        // P^T -> P via wave-private LDS (padded rows: conflict-free b128 read)
        #pragma unroll
        for (int nt = 0; nt < 2; ++nt) {
          bf16x4 w4;
          #pragma unroll
          for (int reg = 0; reg < 4; ++reg) w4[reg] = f2bf(p[nt][reg]);
          *reinterpret_cast<bf16x4*>(&sm.pb[w][j][r][nt * 16 + h * 4]) = w4;
        }
        asm volatile("s_waitcnt lgkmcnt(0)" ::: "memory");
        __builtin_amdgcn_sched_barrier(0);
        ap[j] = *reinterpret_cast<const bf16x8*>(&sm.pb[w][j][r][h * 8]);
      }

      #pragma unroll
      for (int j = 0; j < 2; ++j)
        #pragma unroll
        for (int dt = 0; dt < 8; ++dt)
          acc[j][dt] = __builtin_amdgcn_mfma_f32_16x16x32_bf16(ap[j], vf[dt], acc[j][dt], 0, 0, 0);

      __builtin_amdgcn_sched_barrier(0);
      __builtin_amdgcn_s_barrier();     // both waves done reading buf[cur]
    }
  }

  // ---- epilogue: unnormalized partials ----
  #pragma unroll
  for (int j = 0; j < 2; ++j) {
    if (h == 0) {
      int row = w * 32 + j * 16 + r;
      pml[((size_t)bid * 64 + row) * 2 + 0] = mrun[j];
      pml[((size_t)bid * 64 + row) * 2 + 1] = lrun[j];
    }
    #pragma unroll
    for (int dt = 0; dt < 8; ++dt)
      #pragma unroll
      for (int reg = 0; reg < 4; ++reg) {
        int row = w * 32 + j * 16 + h * 4 + reg;
        pacc[((size_t)bid * 64 + row) * 128 + dt * 16 + r] = acc[j][dt][reg];
      }
  }
}

// Combine 4 kv-chunks: out = sum_c e_c*A_c / sum_c e_c*L_c, e_c = exp(M_c - Ms)
__global__ __launch_bounds__(256) void combine_kernel(const float* __restrict__ pacc,
                                                      const float* __restrict__ pml,
                                                      float* __restrict__ out) {
  int gid = blockIdx.x * 256 + threadIdx.x;   // 262144 threads
  int rg  = gid >> 5;                         // global row 0..8191
  int c4  = (gid & 31) * 4;
  int task = rg >> 6;                         // 0..127
  int row  = rg & 63;
  int qi = 31 - (task >> 2);
  int b  = task & 3;
  int bbase = (task >> 2) * 16 + b * 4;       // attn bid of chunk 0
  float M[4], L[4];
  float Ms = -1e30f;
  #pragma unroll
  for (int cc = 0; cc < 4; ++cc) {
    M[cc] = pml[((size_t)(bbase + cc) * 64 + row) * 2 + 0];
    L[cc] = pml[((size_t)(bbase + cc) * 64 + row) * 2 + 1];
    Ms = fmaxf(Ms, M[cc]);
  }
  float den = 0.0f;
  f32x4 num = {};
  #pragma unroll
  for (int cc = 0; cc < 4; ++cc) {
    float e = __expf(M[cc] - Ms);             // empty chunk: e == 0 exactly
    den += e * L[cc];
    f32x4 a = *reinterpret_cast<const f32x4*>(
        pacc + ((size_t)(bbase + cc) * 64 + row) * 128 + c4);
    num += a * e;
  }
  f32x4 o = num * (1.0f / den);
  *reinterpret_cast<f32x4*>(out + ((size_t)b * Tq + qi * 64 + row) * Dq + c4) = o;
}

extern "C" void kernel_launch(void* const* d_in, const int* in_sizes, int n_in,
                              void* d_out, int out_size, void* d_ws, size_t ws_size,
                              hipStream_t stream) {
  const float* x   = (const float*)d_in[0];
  const float* Wq_ = (const float*)d_in[1];
  const float* Wk_ = (const float*)d_in[2];
  const float* Wv_ = (const float*)d_in[3];
  float* out = (float*)d_out;
  char* ws = (char*)d_ws;
  short* xp   = (short*)(ws);               // 16,777,216 B (dead after gemm)
  short* wp   = (short*)(ws + 16777216);    //    786,432 B
  short* qb   = (short*)(ws + 17563648);    //  2,097,152 B
  short* kb   = (short*)(ws + 19660800);    //  2,097,152 B
  short* vt   = (short*)(ws + 21757952);    //  2,097,152 B
  float* pml  = (float*)(ws + 23855104);    //    262,144 B  (total ~24.1 MB)
  float* pacc = (float*)(ws);               // 16,777,216 B — aliases dead xp

  hipLaunchKernelGGL(pack_x_kernel, dim3(4096), dim3(256), 0, stream, x, xp);
  hipLaunchKernelGGL(pack_w_kernel, dim3(192), dim3(256), 0, stream, Wq_, Wk_, Wv_, wp);
  hipLaunchKernelGGL(qkv_gemm_kernel, dim3(256, 3), dim3(256), 0, stream, xp, wp, qb, kb, vt);
  hipLaunchKernelGGL(attn_kernel, dim3(512), dim3(128), 0, stream, qb, kb, vt, pacc, pml);
  hipLaunchKernelGGL(combine_kernel, dim3(1024), dim3(256), 0, stream, pacc, pml, out);
}

// Round 6
// 63.249 us; speedup vs baseline: 2.1550x; 1.1640x over previous
//
#include <hip/hip_runtime.h>
#include <hip/hip_bf16.h>

typedef __attribute__((ext_vector_type(8))) short bf16x8;
typedef __attribute__((ext_vector_type(4))) short bf16x4;
typedef __attribute__((ext_vector_type(4))) float f32x4;

#define Tq 2048
#define Cq 1024
#define Dq 128

typedef const __attribute__((address_space(1))) void* gas_t;
typedef __attribute__((address_space(3))) void* las_t;

__device__ __forceinline__ short f2bf(float f) {
  unsigned u = __float_as_uint(f);
  u += 0x7fffu + ((u >> 16) & 1u);   // RNE; inputs are finite
  return (short)(u >> 16);
}

// x [8192][1024] fp32 -> xb bf16 row-major (plain cast).
__global__ __launch_bounds__(256) void pack_x_kernel(const float* __restrict__ x,
                                                     short* __restrict__ xb) {
  int tid = blockIdx.x * 256 + threadIdx.x;      // 1,048,576 threads
  size_t e0 = (size_t)tid * 8;
  const float4* src = reinterpret_cast<const float4*>(x + e0);
  float4 v0 = src[0];
  float4 v1 = src[1];
  bf16x8 o;
  o[0]=f2bf(v0.x); o[1]=f2bf(v0.y); o[2]=f2bf(v0.z); o[3]=f2bf(v0.w);
  o[4]=f2bf(v1.x); o[5]=f2bf(v1.y); o[6]=f2bf(v1.z); o[7]=f2bf(v1.w);
  *reinterpret_cast<bf16x8*>(xb + e0) = o;
}

// W [1024][128] fp32 -> wt bf16 transposed [3][128 n][1024 k]; D^-0.5 into Wq.
__global__ __launch_bounds__(256) void pack_w_kernel(const float* __restrict__ Wq_,
                                                     const float* __restrict__ Wk_,
                                                     const float* __restrict__ Wv_,
                                                     short* __restrict__ wt) {
  int tid = blockIdx.x * 256 + threadIdx.x;      // 3*16384 threads
  int y   = tid >> 14;
  int idx = tid & 16383;
  int kg  = idx >> 7;          // k-group of 8
  int n   = idx & 127;
  const float* W = (y == 0) ? Wq_ : (y == 1 ? Wk_ : Wv_);
  float scale = (y == 0) ? 0.08838834764831845f : 1.0f;   // 1/sqrt(128)
  bf16x8 o;
  #pragma unroll
  for (int j = 0; j < 8; ++j) o[j] = f2bf(W[(size_t)(kg * 8 + j) * Dq + n] * scale);
  *reinterpret_cast<bf16x8*>(wt + (size_t)y * 131072 + (size_t)n * 1024 + kg * 8) = o;
}

// QKV GEMM, 2-phase global_load_lds pipeline. grid (256,3), block 128 (2 waves).
// Block tile 32(M) x 128(N), BK=64; wave w owns cols [w*64, w*64+64).
// LDS XOR-swizzled (src-side pre-swizzle, rule 21): col8 ^= (row&7).
__global__ __launch_bounds__(128) void qkv_gemm_kernel(const short* __restrict__ xb,
                                                       const short* __restrict__ wt,
                                                       short* __restrict__ qb,
                                                       short* __restrict__ kb2,
                                                       short* __restrict__ vt) {
  __shared__ short As[2][32][64];    //  8 KB
  __shared__ short Bs[2][128][64];   // 32 KB  (B^T tile: [n][k])
  int y  = blockIdx.y;
  int bm = blockIdx.x;
  int w  = threadIdx.x >> 6, l = threadIdx.x & 63;
  int r  = l & 15, h = l >> 4;
  const short* wy = wt + (size_t)y * 131072;

  auto stage = [&](int t, int bi) {
    int k0 = t * 64;
    #pragma unroll
    for (int i = 0; i < 10; ++i) {
      int ii = w * 10 + i;
      if (ii < 4) {                          // A: 4 insts of 8 rows
        int row = ii * 8 + (l >> 3);
        int sc  = ((l & 7) * 8) ^ ((row & 7) << 3);
        __builtin_amdgcn_global_load_lds(
            (gas_t)(xb + (size_t)(bm * 32 + row) * 1024 + k0 + sc),
            (las_t)(&As[bi][ii * 8][0]), 16, 0, 0);
      } else {                               // B: 16 insts of 8 rows
        int jj  = ii - 4;
        int row = jj * 8 + (l >> 3);
        int sc  = ((l & 7) * 8) ^ ((row & 7) << 3);
        __builtin_amdgcn_global_load_lds(
            (gas_t)(wy + (size_t)row * 1024 + k0 + sc),
            (las_t)(&Bs[bi][jj * 8][0]), 16, 0, 0);
      }
    }
  };

  f32x4 acc[2][4] = {};
  stage(0, 0);
  int cur = 0;
  for (int t = 0; t < 16; ++t, cur ^= 1) {
    stage(t + 1 < 16 ? t + 1 : t, cur ^ 1);
    asm volatile("s_waitcnt vmcnt(10)" ::: "memory");   // my prev 10 landed
    __builtin_amdgcn_s_barrier();                        // other wave's too
    __builtin_amdgcn_sched_barrier(0);
    bf16x8 af[2][2], bf[4][2];
    #pragma unroll
    for (int mi = 0; mi < 2; ++mi)
      #pragma unroll
      for (int kt = 0; kt < 2; ++kt) {
        int row = mi * 16 + r;
        af[mi][kt] = *reinterpret_cast<const bf16x8*>(
            &As[cur][row][(kt * 32 + h * 8) ^ ((row & 7) << 3)]);
      }
    #pragma unroll
    for (int ni = 0; ni < 4; ++ni)
      #pragma unroll
      for (int kt = 0; kt < 2; ++kt) {
        int row = w * 64 + ni * 16 + r;
        bf[ni][kt] = *reinterpret_cast<const bf16x8*>(
            &Bs[cur][row][(kt * 32 + h * 8) ^ ((row & 7) << 3)]);
      }
    #pragma unroll
    for (int kt = 0; kt < 2; ++kt)
      #pragma unroll
      for (int mi = 0; mi < 2; ++mi)
        #pragma unroll
        for (int ni = 0; ni < 4; ++ni)
          acc[mi][ni] = __builtin_amdgcn_mfma_f32_16x16x32_bf16(af[mi][kt], bf[ni][kt], acc[mi][ni], 0, 0, 0);
    __builtin_amdgcn_sched_barrier(0);
    __builtin_amdgcn_s_barrier();            // done reading buf[cur]
  }

  int g = h, c0 = r;
  #pragma unroll
  for (int mi = 0; mi < 2; ++mi) {
    #pragma unroll
    for (int ni = 0; ni < 4; ++ni) {
      #pragma unroll
      for (int reg = 0; reg < 4; ++reg) {
        int m = bm * 32 + mi * 16 + g * 4 + reg;
        int n = w * 64 + ni * 16 + c0;
        short s = f2bf(acc[mi][ni][reg]);
        if (y == 0)      qb[(size_t)m * Dq + n] = s;
        else if (y == 1) kb2[(size_t)m * Dq + n] = s;
        else {
          int bb = m >> 11, t2 = m & 2047;
          vt[((size_t)bb * Dq + n) * Tq + t2] = s;
        }
      }
    }
  }
}

// Causal flash attention with LDS-staged K/V via global_load_lds.
// 1024 blocks x 128 thr (2 waves). bid -> (qi64-tile, batch, kv-chunk c of 8).
// 4 blocks/CU -> 8 waves/CU (2/SIMD). Double-buffered LDS, counted vmcnt(8).
__global__ __launch_bounds__(128) void attn_kernel(const short* __restrict__ qb,
                                                   const short* __restrict__ kb2,
                                                   const short* __restrict__ vtb,
                                                   float* __restrict__ pacc,
                                                   float* __restrict__ pml) {
  __shared__ struct {
    short kb[2][32][128];       // K tile, rows swizzled: [row][c ^ ((row&7)<<3)]
    short vb[2][128][32];       // V^T tile: [d-row][kv ^ ((row&3)<<3)]
    short pb[2][2][16][40];     // per-wave per-subtile P transpose (padded)
  } sm;                         // 37,888 B -> 4 blocks/CU

  int bid = blockIdx.x;
  int qi  = 31 - (bid >> 5);           // long tasks dispatched first
  int b   = (bid >> 3) & 3;
  int c   = bid & 7;
  int tid = threadIdx.x;
  int w   = tid >> 6, l = tid & 63;
  int r   = l & 15, h = l >> 4;

  int q0 = qi * 64;
  int qw = q0 + w * 32;                // wave's first q row
  const short* kbB = kb2 + (size_t)b * Tq * Dq;
  const short* vtB = vtb + (size_t)b * Dq * Tq;

  // Q frags (B-operand layout): subtile j rows [qw+j*16, +16)
  bf16x8 aq[2][4];
  #pragma unroll
  for (int j = 0; j < 2; ++j) {
    size_t qbase = ((size_t)b * Tq + qw + j * 16 + r) * Dq;
    #pragma unroll
    for (int kt = 0; kt < 4; ++kt)
      aq[j][kt] = *reinterpret_cast<const bf16x8*>(qb + qbase + kt * 32 + h * 8);
  }

  int ntall = 2 * qi + 2;              // kv tiles of 32 covering [0, q0+64)
  int clen  = (ntall + 7) >> 3;
  int tbeg  = c * clen;
  int tend  = ntall < tbeg + clen ? ntall : tbeg + clen;

  f32x4 acc[2][8] = {};
  float mrun[2] = {-1e30f, -1e30f}, lrun[2] = {0.0f, 0.0f};

  if (tbeg < tend) {
    auto stage = [&](int it, int bi) {
      int kv0 = it * 32;
      #pragma unroll
      for (int i2 = 0; i2 < 4; ++i2) {          // K: 1 KB per inst
        int i = w * 4 + i2;
        int row = i * 4 + (l >> 4);
        int sc  = ((l & 15) * 8) ^ ((row & 7) << 3);
        __builtin_amdgcn_global_load_lds(
            (gas_t)(kbB + (size_t)(kv0 + row) * Dq + sc),
            (las_t)(&sm.kb[bi][i * 4][0]), 16, 0, 0);
      }
      #pragma unroll
      for (int i2 = 0; i2 < 4; ++i2) {          // V: 1 KB per inst
        int i = w * 4 + i2;
        int row = i * 16 + (l >> 2);
        int sc  = ((l & 3) * 8) ^ ((row & 3) << 3);
        __builtin_amdgcn_global_load_lds(
            (gas_t)(vtB + (size_t)row * Tq + kv0 + sc),
            (las_t)(&sm.vb[bi][i * 16][0]), 16, 0, 0);
      }
    };

    stage(tbeg, 0);
    int cur = 0;
    for (int t = tbeg; t < tend; ++t, cur ^= 1) {
      int pf = (t + 1 < tend) ? t + 1 : t;      // always issue 8 (vmcnt math)
      stage(pf, cur ^ 1);
      asm volatile("s_waitcnt vmcnt(8)" ::: "memory");  // cur's loads landed (mine)
      __builtin_amdgcn_s_barrier();                      // ...and the other wave's
      __builtin_amdgcn_sched_barrier(0);

      int kv0 = t * 32;
      // K frags from LDS (shared across both subtiles)
      bf16x8 kf[8];
      #pragma unroll
      for (int nt = 0; nt < 2; ++nt)
        #pragma unroll
        for (int kt = 0; kt < 4; ++kt) {
          int row = nt * 16 + r;
          kf[nt * 4 + kt] = *reinterpret_cast<const bf16x8*>(
              &sm.kb[cur][row][(kt * 32 + h * 8) ^ ((row & 7) << 3)]);
        }
      f32x4 s[2][2] = {};
      #pragma unroll
      for (int j = 0; j < 2; ++j)
        #pragma unroll
        for (int nt = 0; nt < 2; ++nt)
          #pragma unroll
          for (int kt = 0; kt < 4; ++kt)
            s[j][nt] = __builtin_amdgcn_mfma_f32_16x16x32_bf16(
                kf[nt * 4 + kt], aq[j][kt], s[j][nt], 0, 0, 0);

      // V frags (ds_reads overlap softmax below)
      bf16x8 vf[8];
      #pragma unroll
      for (int dt = 0; dt < 8; ++dt) {
        int row = dt * 16 + r;
        vf[dt] = *reinterpret_cast<const bf16x8*>(
            &sm.vb[cur][row][(h * 8) ^ ((row & 3) << 3)]);
      }

      // causal mask (kv > q)
      #pragma unroll
      for (int j = 0; j < 2; ++j) {
        int qb_j = qw + j * 16;
        if (kv0 + 31 > qb_j) {
          #pragma unroll
          for (int nt = 0; nt < 2; ++nt)
            #pragma unroll
            for (int reg = 0; reg < 4; ++reg)
              if (kv0 + nt * 16 + h * 4 + reg > qb_j + r) s[j][nt][reg] = -1e30f;
        }
      }

      // two independent per-subtile softmax chains; single LDS wait for both
      #pragma unroll
      for (int j = 0; j < 2; ++j) {
        float mx = fmaxf(fmaxf(fmaxf(s[j][0][0], s[j][0][1]), fmaxf(s[j][0][2], s[j][0][3])),
                         fmaxf(fmaxf(s[j][1][0], s[j][1][1]), fmaxf(s[j][1][2], s[j][1][3])));
        mx = fmaxf(mx, __shfl_xor(mx, 16));
        mx = fmaxf(mx, __shfl_xor(mx, 32));
        float mnew  = fmaxf(mrun[j], mx);
        float alpha = __expf(mrun[j] - mnew);
        mrun[j] = mnew;
        float p[2][4];
        #pragma unroll
        for (int nt = 0; nt < 2; ++nt)
          #pragma unroll
          for (int reg = 0; reg < 4; ++reg)
            p[nt][reg] = s[j][nt][reg] > -1e29f ? __expf(s[j][nt][reg] - mnew) : 0.0f;
        float rsum = ((p[0][0] + p[0][1]) + (p[0][2] + p[0][3])) +
                     ((p[1][0] + p[1][1]) + (p[1][2] + p[1][3]));
        rsum += __shfl_xor(rsum, 16);
        rsum += __shfl_xor(rsum, 32);
        lrun[j] = lrun[j] * alpha + rsum;

        float af[4];
        #pragma unroll
        for (int reg = 0; reg < 4; ++reg) af[reg] = __shfl(alpha, h * 4 + reg);
        #pragma unroll
        for (int dt = 0; dt < 8; ++dt)
          #pragma unroll
          for (int reg = 0; reg < 4; ++reg) acc[j][dt][reg] *= af[reg];

        #pragma unroll
        for (int nt = 0; nt < 2; ++nt) {
          bf16x4 w4;
          #pragma unroll
          for (int reg = 0; reg < 4; ++reg) w4[reg] = f2bf(p[nt][reg]);
          *reinterpret_cast<bf16x4*>(&sm.pb[w][j][r][nt * 16 + h * 4]) = w4;
        }
      }
      asm volatile("s_waitcnt lgkmcnt(0)" ::: "memory");
      __builtin_amdgcn_sched_barrier(0);
      bf16x8 ap[2];
      ap[0] = *reinterpret_cast<const bf16x8*>(&sm.pb[w][0][r][h * 8]);
      ap[1] = *reinterpret_cast<const bf16x8*>(&sm.pb[w][1][r][h * 8]);

      #pragma unroll
      for (int j = 0; j < 2; ++j)
        #pragma unroll
        for (int dt = 0; dt < 8; ++dt)
          acc[j][dt] = __builtin_amdgcn_mfma_f32_16x16x32_bf16(ap[j], vf[dt], acc[j][dt], 0, 0, 0);

      __builtin_amdgcn_sched_barrier(0);
      __builtin_amdgcn_s_barrier();     // both waves done reading buf[cur]
    }
  }

  // ---- epilogue: unnormalized partials ----
  #pragma unroll
  for (int j = 0; j < 2; ++j) {
    if (h == 0) {
      int row = w * 32 + j * 16 + r;
      pml[((size_t)bid * 64 + row) * 2 + 0] = mrun[j];
      pml[((size_t)bid * 64 + row) * 2 + 1] = lrun[j];
    }
    #pragma unroll
    for (int dt = 0; dt < 8; ++dt)
      #pragma unroll
      for (int reg = 0; reg < 4; ++reg) {
        int row = w * 32 + j * 16 + h * 4 + reg;
        pacc[((size_t)bid * 64 + row) * 128 + dt * 16 + r] = acc[j][dt][reg];
      }
  }
}

// Combine 8 kv-chunks: out = sum_c e_c*A_c / sum_c e_c*L_c, e_c = exp(M_c - Ms)
__global__ __launch_bounds__(256) void combine_kernel(const float* __restrict__ pacc,
                                                      const float* __restrict__ pml,
                                                      float* __restrict__ out) {
  int gid = blockIdx.x * 256 + threadIdx.x;   // 262144 threads
  int rg  = gid >> 5;                         // global row 0..8191
  int c4  = (gid & 31) * 4;
  int task = rg >> 6;                         // 0..127
  int row  = rg & 63;
  int qi = 31 - (task >> 2);
  int b  = task & 3;
  int bbase = task * 8;                       // attn bid of chunk 0
  float M[8], L[8];
  float Ms = -1e30f;
  #pragma unroll
  for (int cc = 0; cc < 8; ++cc) {
    M[cc] = pml[((size_t)(bbase + cc) * 64 + row) * 2 + 0];
    L[cc] = pml[((size_t)(bbase + cc) * 64 + row) * 2 + 1];
    Ms = fmaxf(Ms, M[cc]);
  }
  float den = 0.0f;
  f32x4 num = {};
  #pragma unroll
  for (int cc = 0; cc < 8; ++cc) {
    float e = __expf(M[cc] - Ms);             // empty chunk: e == 0 exactly
    den += e * L[cc];
    f32x4 a = *reinterpret_cast<const f32x4*>(
        pacc + ((size_t)(bbase + cc) * 64 + row) * 128 + c4);
    num += a * e;
  }
  f32x4 o = num * (1.0f / den);
  *reinterpret_cast<f32x4*>(out + ((size_t)b * Tq + qi * 64 + row) * Dq + c4) = o;
}

extern "C" void kernel_launch(void* const* d_in, const int* in_sizes, int n_in,
                              void* d_out, int out_size, void* d_ws, size_t ws_size,
                              hipStream_t stream) {
  const float* x   = (const float*)d_in[0];
  const float* Wq_ = (const float*)d_in[1];
  const float* Wk_ = (const float*)d_in[2];
  const float* Wv_ = (const float*)d_in[3];
  float* out = (float*)d_out;
  char* ws = (char*)d_ws;
  short* xb   = (short*)(ws);               // 16,777,216 B  x bf16 row-major
  short* wt   = (short*)(ws + 16777216);    //    786,432 B  W^T bf16 [3][128][1024]
  short* qb   = (short*)(ws + 17563648);    //  2,097,152 B  q row-major (pre-scaled)
  short* kb   = (short*)(ws + 19660800);    //  2,097,152 B  k row-major
  short* vt   = (short*)(ws + 21757952);    //  2,097,152 B  v^T [b][d][t]
  float* pml  = (float*)(ws + 23855104);    //    524,288 B
  float* pacc = (float*)(ws + 24379392);    // 33,554,432 B  (total ~58 MB)

  hipLaunchKernelGGL(pack_x_kernel, dim3(4096), dim3(256), 0, stream, x, xb);
  hipLaunchKernelGGL(pack_w_kernel, dim3(192), dim3(256), 0, stream, Wq_, Wk_, Wv_, wt);
  hipLaunchKernelGGL(qkv_gemm_kernel, dim3(256, 3), dim3(128), 0, stream, xb, wt, qb, kb, vt);
  hipLaunchKernelGGL(attn_kernel, dim3(1024), dim3(128), 0, stream, qb, kb, vt, pacc, pml);
  hipLaunchKernelGGL(combine_kernel, dim3(1024), dim3(256), 0, stream, pacc, pml, out);
}

// Round 7
// 56.627 us; speedup vs baseline: 2.4070x; 1.1169x over previous
//
#include <hip/hip_runtime.h>
#include <hip/hip_bf16.h>

typedef __attribute__((ext_vector_type(8))) short bf16x8;
typedef __attribute__((ext_vector_type(4))) short bf16x4;
typedef __attribute__((ext_vector_type(4))) float f32x4;

#define Tq 2048
#define Cq 1024
#define Dq 128

typedef const __attribute__((address_space(1))) void* gas_t;
typedef __attribute__((address_space(3))) void* las_t;

__device__ __forceinline__ short f2bf(float f) {
  unsigned u = __float_as_uint(f);
  u += 0x7fffu + ((u >> 16) & 1u);   // RNE; inputs are finite
  return (short)(u >> 16);
}

// W [1024][128] fp32 -> wt bf16 transposed [3][128 n][1024 k]; D^-0.5 into Wq.
__global__ __launch_bounds__(256) void pack_w_kernel(const float* __restrict__ Wq_,
                                                     const float* __restrict__ Wk_,
                                                     const float* __restrict__ Wv_,
                                                     short* __restrict__ wt) {
  int tid = blockIdx.x * 256 + threadIdx.x;      // 3*16384 threads
  int y   = tid >> 14;
  int idx = tid & 16383;
  int kg  = idx >> 7;          // k-group of 8
  int n   = idx & 127;
  const float* W = (y == 0) ? Wq_ : (y == 1 ? Wk_ : Wv_);
  float scale = (y == 0) ? 0.08838834764831845f : 1.0f;   // 1/sqrt(128)
  bf16x8 o;
  #pragma unroll
  for (int j = 0; j < 8; ++j) o[j] = f2bf(W[(size_t)(kg * 8 + j) * Dq + n] * scale);
  *reinterpret_cast<bf16x8*>(wt + (size_t)y * 131072 + (size_t)n * 1024 + kg * 8) = o;
}

// QKV GEMM, 2-phase global_load_lds pipeline, x read DIRECTLY as fp32
// (pack_x eliminated; A converted bf16 at ds_read via v_cvt_pk_bf16_f32).
// grid (256,3), block 128 (2 waves). Tile 32(M) x 128(N), BK=64.
__global__ __launch_bounds__(128) void qkv_gemm_kernel(const float* __restrict__ x,
                                                       const short* __restrict__ wt,
                                                       short* __restrict__ qb,
                                                       short* __restrict__ kb2,
                                                       short* __restrict__ vt) {
  __shared__ float As[2][32][64];    // 16 KB fp32 A tile, granule16-swizzled
  __shared__ short Bs[2][128][64];   // 32 KB B^T tile
  int y  = blockIdx.y;
  int bm = blockIdx.x;
  int w  = threadIdx.x >> 6, l = threadIdx.x & 63;
  int r  = l & 15, h = l >> 4;
  const short* wy = wt + (size_t)y * 131072;

  auto stage = [&](int t, int bi) {
    int k0 = t * 64;
    #pragma unroll
    for (int i = 0; i < 4; ++i) {            // A: 8 insts of 4 rows (fp32)
      int ia  = w * 4 + i;
      int row = ia * 4 + (l >> 4);
      int g   = l & 15;                      // 16B granule in 256B row
      int sg  = (g & 8) | ((g & 7) ^ (row & 7));
      __builtin_amdgcn_global_load_lds(
          (gas_t)(x + (size_t)(bm * 32 + row) * Cq + k0 + sg * 4),
          (las_t)(&As[bi][ia * 4][0]), 16, 0, 0);
    }
    #pragma unroll
    for (int i = 0; i < 8; ++i) {            // B: 16 insts of 8 rows (bf16)
      int ib  = w * 8 + i;
      int row = ib * 8 + (l >> 3);
      int sc  = ((l & 7) ^ (row & 7)) * 8;
      __builtin_amdgcn_global_load_lds(
          (gas_t)(wy + (size_t)row * Cq + k0 + sc),
          (las_t)(&Bs[bi][ib * 8][0]), 16, 0, 0);
    }
  };

  f32x4 acc[2][4] = {};
  stage(0, 0);
  int cur = 0;
  for (int t = 0; t < 16; ++t, cur ^= 1) {
    stage(t + 1 < 16 ? t + 1 : t, cur ^ 1);
    asm volatile("s_waitcnt vmcnt(12)" ::: "memory");   // my prev 12 landed
    __builtin_amdgcn_s_barrier();                        // other wave's too
    __builtin_amdgcn_sched_barrier(0);
    bf16x8 af[2][2], bf[4][2];
    #pragma unroll
    for (int mi = 0; mi < 2; ++mi)
      #pragma unroll
      for (int kt = 0; kt < 2; ++kt) {
        int row = mi * 16 + r;
        int g0  = kt * 8 + h * 2;
        int s0  = (g0 & 8) | ((g0 & 7) ^ (row & 7));
        int g1  = g0 + 1;
        int s1  = (g1 & 8) | ((g1 & 7) ^ (row & 7));
        f32x4 fa = *reinterpret_cast<const f32x4*>(&As[cur][row][s0 * 4]);
        f32x4 fb = *reinterpret_cast<const f32x4*>(&As[cur][row][s1 * 4]);
        union { bf16x8 v; unsigned u[4]; } cv;
        asm("v_cvt_pk_bf16_f32 %0, %1, %2" : "=v"(cv.u[0]) : "v"(fa[0]), "v"(fa[1]));
        asm("v_cvt_pk_bf16_f32 %0, %1, %2" : "=v"(cv.u[1]) : "v"(fa[2]), "v"(fa[3]));
        asm("v_cvt_pk_bf16_f32 %0, %1, %2" : "=v"(cv.u[2]) : "v"(fb[0]), "v"(fb[1]));
        asm("v_cvt_pk_bf16_f32 %0, %1, %2" : "=v"(cv.u[3]) : "v"(fb[2]), "v"(fb[3]));
        af[mi][kt] = cv.v;
      }
    #pragma unroll
    for (int ni = 0; ni < 4; ++ni)
      #pragma unroll
      for (int kt = 0; kt < 2; ++kt) {
        int row = w * 64 + ni * 16 + r;
        bf[ni][kt] = *reinterpret_cast<const bf16x8*>(
            &Bs[cur][row][(kt * 32 + h * 8) ^ ((row & 7) << 3)]);
      }
    #pragma unroll
    for (int kt = 0; kt < 2; ++kt)
      #pragma unroll
      for (int mi = 0; mi < 2; ++mi)
        #pragma unroll
        for (int ni = 0; ni < 4; ++ni)
          acc[mi][ni] = __builtin_amdgcn_mfma_f32_16x16x32_bf16(af[mi][kt], bf[ni][kt], acc[mi][ni], 0, 0, 0);
    __builtin_amdgcn_sched_barrier(0);
    __builtin_amdgcn_s_barrier();            // done reading buf[cur]
  }

  #pragma unroll
  for (int mi = 0; mi < 2; ++mi) {
    #pragma unroll
    for (int ni = 0; ni < 4; ++ni) {
      #pragma unroll
      for (int reg = 0; reg < 4; ++reg) {
        int m = bm * 32 + mi * 16 + h * 4 + reg;
        int n = w * 64 + ni * 16 + r;
        short s = f2bf(acc[mi][ni][reg]);
        if (y == 0)      qb[(size_t)m * Dq + n] = s;
        else if (y == 1) kb2[(size_t)m * Dq + n] = s;
        else {
          int bb = m >> 11, t2 = m & 2047;
          vt[((size_t)bb * Dq + n) * Tq + t2] = s;
        }
      }
    }
  }
}

// Causal flash attention. 1024 blocks x 256 thr (4 waves), forced 4 blocks/CU
// -> 16 waves/CU (4/SIMD). bid -> (qi64-tile, batch, kv-chunk c of 8).
// Wave w owns 16 q-rows; all 4 waves share one K/V double-buffered pipeline
// (stage split 4 ways, counted vmcnt(4), raw barriers).
__global__ __launch_bounds__(256, 4) void attn_kernel(const short* __restrict__ qb,
                                                      const short* __restrict__ kb2,
                                                      const short* __restrict__ vtb,
                                                      float* __restrict__ pacc,
                                                      float* __restrict__ pml) {
  __shared__ struct {
    short kb[2][32][128];       // K tile, swizzled: [row][c ^ ((row&7)<<3)]
    short vb[2][128][32];       // V^T tile: [d-row][kv ^ ((row&3)<<3)]
    short pb[4][16][40];        // per-wave P transpose (padded rows)
  } sm;                         // 37,888 B

  int bid = blockIdx.x;
  int qi  = 31 - (bid >> 5);           // long tasks dispatched first
  int b   = (bid >> 3) & 3;
  int c   = bid & 7;
  int tid = threadIdx.x;
  int w   = tid >> 6, l = tid & 63;
  int r   = l & 15, h = l >> 4;

  int qw = qi * 64 + w * 16;           // wave's 16 q-rows
  const short* kbB = kb2 + (size_t)b * Tq * Dq;
  const short* vtB = vtb + (size_t)b * Dq * Tq;

  // Q frags (B-operand layout)
  bf16x8 aq[4];
  size_t qbase = ((size_t)b * Tq + qw + r) * Dq;
  #pragma unroll
  for (int kt = 0; kt < 4; ++kt)
    aq[kt] = *reinterpret_cast<const bf16x8*>(qb + qbase + kt * 32 + h * 8);

  int ntall = 2 * qi + 2;              // kv tiles of 32 covering [0, qi*64+64)
  int clen  = (ntall + 7) >> 3;
  int tbeg  = c * clen;
  int tend  = ntall < tbeg + clen ? ntall : tbeg + clen;

  f32x4 acc[8] = {};
  float mrun = -1e30f, lrun = 0.0f;

  if (tbeg < tend) {
    auto stage = [&](int it, int bi) {
      int kv0 = it * 32;
      #pragma unroll
      for (int i2 = 0; i2 < 2; ++i2) {          // K: 2 insts/wave
        int i = w * 2 + i2;
        int row = i * 4 + (l >> 4);
        int sc  = ((l & 15) * 8) ^ ((row & 7) << 3);
        __builtin_amdgcn_global_load_lds(
            (gas_t)(kbB + (size_t)(kv0 + row) * Dq + sc),
            (las_t)(&sm.kb[bi][i * 4][0]), 16, 0, 0);
      }
      #pragma unroll
      for (int i2 = 0; i2 < 2; ++i2) {          // V: 2 insts/wave
        int i = w * 2 + i2;
        int row = i * 16 + (l >> 2);
        int sc  = ((l & 3) * 8) ^ ((row & 3) << 3);
        __builtin_amdgcn_global_load_lds(
            (gas_t)(vtB + (size_t)row * Tq + kv0 + sc),
            (las_t)(&sm.vb[bi][i * 16][0]), 16, 0, 0);
      }
    };

    stage(tbeg, 0);
    int cur = 0;
    for (int t = tbeg; t < tend; ++t, cur ^= 1) {
      stage(t + 1 < tend ? t + 1 : t, cur ^ 1);  // always 4 insts (vmcnt math)
      asm volatile("s_waitcnt vmcnt(4)" ::: "memory");
      __builtin_amdgcn_s_barrier();
      __builtin_amdgcn_sched_barrier(0);

      int kv0 = t * 32;
      bf16x8 kf[8];
      #pragma unroll
      for (int nt = 0; nt < 2; ++nt)
        #pragma unroll
        for (int kt = 0; kt < 4; ++kt) {
          int row = nt * 16 + r;
          kf[nt * 4 + kt] = *reinterpret_cast<const bf16x8*>(
              &sm.kb[cur][row][(kt * 32 + h * 8) ^ ((row & 7) << 3)]);
        }
      f32x4 s[2] = {};
      #pragma unroll
      for (int nt = 0; nt < 2; ++nt)
        #pragma unroll
        for (int kt = 0; kt < 4; ++kt)
          s[nt] = __builtin_amdgcn_mfma_f32_16x16x32_bf16(
              kf[nt * 4 + kt], aq[kt], s[nt], 0, 0, 0);

      bf16x8 vf[8];
      #pragma unroll
      for (int dt = 0; dt < 8; ++dt) {
        int row = dt * 16 + r;
        vf[dt] = *reinterpret_cast<const bf16x8*>(
            &sm.vb[cur][row][(h * 8) ^ ((row & 3) << 3)]);
      }

      // causal mask (kv > q); lane q-row = qw + r
      if (kv0 + 31 > qw) {
        #pragma unroll
        for (int nt = 0; nt < 2; ++nt)
          #pragma unroll
          for (int reg = 0; reg < 4; ++reg)
            if (kv0 + nt * 16 + h * 4 + reg > qw + r) s[nt][reg] = -1e30f;
      }

      float mx = fmaxf(fmaxf(fmaxf(s[0][0], s[0][1]), fmaxf(s[0][2], s[0][3])),
                       fmaxf(fmaxf(s[1][0], s[1][1]), fmaxf(s[1][2], s[1][3])));
      mx = fmaxf(mx, __shfl_xor(mx, 16));
      mx = fmaxf(mx, __shfl_xor(mx, 32));
      float mnew  = fmaxf(mrun, mx);
      float alpha = __expf(mrun - mnew);
      mrun = mnew;
      float p[2][4];
      #pragma unroll
      for (int nt = 0; nt < 2; ++nt)
        #pragma unroll
        for (int reg = 0; reg < 4; ++reg)
          p[nt][reg] = s[nt][reg] > -1e29f ? __expf(s[nt][reg] - mnew) : 0.0f;
      float rsum = ((p[0][0] + p[0][1]) + (p[0][2] + p[0][3])) +
                   ((p[1][0] + p[1][1]) + (p[1][2] + p[1][3]));
      rsum += __shfl_xor(rsum, 16);
      rsum += __shfl_xor(rsum, 32);
      lrun = lrun * alpha + rsum;

      float af[4];
      #pragma unroll
      for (int reg = 0; reg < 4; ++reg) af[reg] = __shfl(alpha, h * 4 + reg);
      #pragma unroll
      for (int dt = 0; dt < 8; ++dt)
        #pragma unroll
        for (int reg = 0; reg < 4; ++reg) acc[dt][reg] *= af[reg];

      // P^T -> P via wave-private LDS (in-order DS per wave: single buffer)
      #pragma unroll
      for (int nt = 0; nt < 2; ++nt) {
        bf16x4 w4;
        #pragma unroll
        for (int reg = 0; reg < 4; ++reg) w4[reg] = f2bf(p[nt][reg]);
        *reinterpret_cast<bf16x4*>(&sm.pb[w][r][nt * 16 + h * 4]) = w4;
      }
      asm volatile("s_waitcnt lgkmcnt(0)" ::: "memory");
      __builtin_amdgcn_sched_barrier(0);
      bf16x8 ap = *reinterpret_cast<const bf16x8*>(&sm.pb[w][r][h * 8]);

      #pragma unroll
      for (int dt = 0; dt < 8; ++dt)
        acc[dt] = __builtin_amdgcn_mfma_f32_16x16x32_bf16(ap, vf[dt], acc[dt], 0, 0, 0);

      __builtin_amdgcn_sched_barrier(0);
      __builtin_amdgcn_s_barrier();     // all waves done reading buf[cur]
    }
  }

  // ---- epilogue: unnormalized partials ----
  if (h == 0) {
    pml[((size_t)bid * 64 + w * 16 + r) * 2 + 0] = mrun;
    pml[((size_t)bid * 64 + w * 16 + r) * 2 + 1] = lrun;
  }
  #pragma unroll
  for (int dt = 0; dt < 8; ++dt)
    #pragma unroll
    for (int reg = 0; reg < 4; ++reg) {
      int row = w * 16 + h * 4 + reg;
      pacc[((size_t)bid * 64 + row) * 128 + dt * 16 + r] = acc[dt][reg];
    }
}

// Combine 8 kv-chunks: out = sum_c e_c*A_c / sum_c e_c*L_c, e_c = exp(M_c - Ms)
__global__ __launch_bounds__(256) void combine_kernel(const float* __restrict__ pacc,
                                                      const float* __restrict__ pml,
                                                      float* __restrict__ out) {
  int gid = blockIdx.x * 256 + threadIdx.x;   // 262144 threads
  int rg  = gid >> 5;                         // global row 0..8191
  int c4  = (gid & 31) * 4;
  int task = rg >> 6;                         // 0..127
  int row  = rg & 63;
  int qi = 31 - (task >> 2);
  int b  = task & 3;
  int bbase = task * 8;                       // attn bid of chunk 0
  float M[8], L[8];
  float Ms = -1e30f;
  #pragma unroll
  for (int cc = 0; cc < 8; ++cc) {
    M[cc] = pml[((size_t)(bbase + cc) * 64 + row) * 2 + 0];
    L[cc] = pml[((size_t)(bbase + cc) * 64 + row) * 2 + 1];
    Ms = fmaxf(Ms, M[cc]);
  }
  float den = 0.0f;
  f32x4 num = {};
  #pragma unroll
  for (int cc = 0; cc < 8; ++cc) {
    float e = __expf(M[cc] - Ms);             // empty chunk: e == 0 exactly
    den += e * L[cc];
    f32x4 a = *reinterpret_cast<const f32x4*>(
        pacc + ((size_t)(bbase + cc) * 64 + row) * 128 + c4);
    num += a * e;
  }
  f32x4 o = num * (1.0f / den);
  *reinterpret_cast<f32x4*>(out + ((size_t)b * Tq + qi * 64 + row) * Dq + c4) = o;
}

extern "C" void kernel_launch(void* const* d_in, const int* in_sizes, int n_in,
                              void* d_out, int out_size, void* d_ws, size_t ws_size,
                              hipStream_t stream) {
  const float* x   = (const float*)d_in[0];
  const float* Wq_ = (const float*)d_in[1];
  const float* Wk_ = (const float*)d_in[2];
  const float* Wv_ = (const float*)d_in[3];
  float* out = (float*)d_out;
  char* ws = (char*)d_ws;
  short* wt   = (short*)(ws);               //    786,432 B  W^T bf16 [3][128][1024]
  short* qb   = (short*)(ws + 786432);      //  2,097,152 B  q row-major (pre-scaled)
  short* kb   = (short*)(ws + 2883584);     //  2,097,152 B  k row-major
  short* vt   = (short*)(ws + 4980736);     //  2,097,152 B  v^T [b][d][t]
  float* pml  = (float*)(ws + 7077888);     //    524,288 B
  float* pacc = (float*)(ws + 7602176);     // 33,554,432 B  (total ~41 MB)

  hipLaunchKernelGGL(pack_w_kernel, dim3(192), dim3(256), 0, stream, Wq_, Wk_, Wv_, wt);
  hipLaunchKernelGGL(qkv_gemm_kernel, dim3(256, 3), dim3(128), 0, stream, x, wt, qb, kb, vt);
  hipLaunchKernelGGL(attn_kernel, dim3(1024), dim3(256), 0, stream, qb, kb, vt, pacc, pml);
  hipLaunchKernelGGL(combine_kernel, dim3(1024), dim3(256), 0, stream, pacc, pml, out);
}